// Round 12
// baseline (134.854 us; speedup 1.0000x reference)
//
#include <hip/hip_runtime.h>
#include <hip/hip_bf16.h>

#define NREL 8
#define CH   64   // IN_CH == HID_CH == 64
#define NPB  16   // nodes per block in fused agg+gemm

typedef unsigned int uint32;
typedef __attribute__((ext_vector_type(8))) short bf16x8;
typedef __attribute__((ext_vector_type(4))) float f32x4;
union U4 { uint4 u; bf16x8 v; };

// ---- bf16 helpers (RNE) ----------------------------------------------------
static __device__ __forceinline__ uint32 packbf(float a, float b) {
    uint32 ua = __float_as_uint(a), ub = __float_as_uint(b);
    ua = (ua + 0x7fffu + ((ua >> 16) & 1u)) >> 16;          // low half  (elem 0 = even k)
    ub = (ub + 0x7fffu + ((ub >> 16) & 1u)) & 0xffff0000u;  // high half (elem 1 = odd k)
    return ua | ub;
}
static __device__ __forceinline__ float bflo(uint32 w) { return __uint_as_float(w << 16); }
static __device__ __forceinline__ float bfhi(uint32 w) { return __uint_as_float(w & 0xffff0000u); }

// ---------------------------------------------------------------------------
// prep: blocks [0,16) build B-fragments from W; the rest pack x into bf16.
// ---------------------------------------------------------------------------
__global__ __launch_bounds__(256) void prep_k(
    const float* __restrict__ x, uint32* __restrict__ xbf,
    const float* __restrict__ Wf, uint32* __restrict__ Bfrag, int n2)
{
    if (blockIdx.x < 16) {
        const int idx  = blockIdx.x * 256 + threadIdx.x;   // 0..4095
        const int lane = idx & 63;
        const int c    = (idx >> 6) & 3;
        const int ks   = idx >> 8;                          // 0..15
        const int col  = c * 16 + (lane & 15);
        const int k0   = ks * 32 + (lane >> 4) * 8;
        uint4 o;
        o.x = packbf(Wf[(k0 + 0) * 64 + col], Wf[(k0 + 1) * 64 + col]);
        o.y = packbf(Wf[(k0 + 2) * 64 + col], Wf[(k0 + 3) * 64 + col]);
        o.z = packbf(Wf[(k0 + 4) * 64 + col], Wf[(k0 + 5) * 64 + col]);
        o.w = packbf(Wf[(k0 + 6) * 64 + col], Wf[(k0 + 7) * 64 + col]);
        *(uint4*)(Bfrag + (size_t)idx * 4) = o;
    } else {
        const int i = (blockIdx.x - 16) * 256 + threadIdx.x;
        if (i < n2) {
            const float2 v = ((const float2*)x)[i];
            xbf[i] = packbf(v.x, v.y);
        }
    }
}

// ---------------------------------------------------------------------------
// Coarse histogram over c = dst>>8: per-block partials (no global atomics).
// ---------------------------------------------------------------------------
__global__ __launch_bounds__(256) void chist_k(
    const int* __restrict__ ei, int* __restrict__ cpart, int nE, int nT)
{
    __shared__ int h[256];
    h[threadIdx.x] = 0;
    __syncthreads();
    for (int e = blockIdx.x * 256 + threadIdx.x; e < nE; e += nT)
        atomicAdd(&h[ei[nE + e] >> 8], 1);
    __syncthreads();
    cpart[blockIdx.x * 256 + threadIdx.x] = h[threadIdx.x];
}

// ---------------------------------------------------------------------------
// Column-sum partials + exclusive scan -> cbase[0..NC], ccur.
// ---------------------------------------------------------------------------
__global__ __launch_bounds__(256) void cscan_k(
    const int* __restrict__ cpart, int* __restrict__ cbase,
    int* __restrict__ ccur, int NC, int nHB)
{
    __shared__ int sc[256];
    const int t = threadIdx.x;
    int v = 0;
    for (int b = 0; b < nHB; ++b) v += cpart[b * 256 + t];
    sc[t] = v;
    __syncthreads();
    for (int off = 1; off < 256; off <<= 1) {
        int add = (t >= off) ? sc[t - off] : 0;
        __syncthreads();
        sc[t] += add;
        __syncthreads();
    }
    const int ex = sc[t] - v;
    if (t < NC) { cbase[t] = ex; ccur[t] = ex; }
    if (t == 255) cbase[NC] = sc[255];
}

// ---------------------------------------------------------------------------
// Coarse binning: per 2048-edge chunk, stage in LDS, reserve runs, write runs.
// Entry pack: (dlow<<24)|(rel<<16)|src.
// ---------------------------------------------------------------------------
__global__ __launch_bounds__(256) void bin_k(
    const int* __restrict__ ei, const int* __restrict__ rel,
    int* __restrict__ ccur, uint32* __restrict__ binned, int nE)
{
    __shared__ uint32        ent[2048];
    __shared__ unsigned char cid[2048];
    __shared__ int lh[256], lb[256], lc[256];

    const int t = threadIdx.x;
    lh[t] = 0;
    __syncthreads();

    const int base = blockIdx.x * 2048;
    #pragma unroll
    for (int i = 0; i < 8; ++i) {
        const int idx = t + i * 256;
        const int e   = base + idx;
        if (e < nE) {
            const int dst = ei[nE + e];
            ent[idx] = ((uint32)(dst & 255) << 24) | ((uint32)rel[e] << 16) | (uint32)ei[e];
            const int c = dst >> 8;
            cid[idx] = (unsigned char)c;
            atomicAdd(&lh[c], 1);
        } else {
            cid[idx] = 255;   // sentinel (NC <= 254 guard in launcher)
        }
    }
    __syncthreads();

    if (lh[t]) lb[t] = atomicAdd(&ccur[t], lh[t]);
    lc[t] = 0;
    __syncthreads();

    #pragma unroll
    for (int i = 0; i < 8; ++i) {
        const int idx = t + i * 256;
        const int c   = cid[idx];
        if (c != 255) {
            const int off = atomicAdd(&lc[c], 1);
            binned[lb[c] + off] = ent[idx];
        }
    }
}

// ---------------------------------------------------------------------------
// Fine sort within one coarse bucket (keyspace 2048 = dlow*8+rel), in LDS.
// sorted[] keeps (rel<<16)|src. Also accumulates the per-degree node counts
// (deg capped at 63) into global dcnt for the balance permutation.
// ---------------------------------------------------------------------------
__global__ __launch_bounds__(1024) void fsort_k(
    const uint32* __restrict__ binned, const int* __restrict__ cbase,
    int* __restrict__ start, int* __restrict__ sorted,
    int* __restrict__ dcnt, int NC, int nN)
{
    __shared__ int fh[2048], fex[2048], fcur[2048], sc[1024], ldc[64];
    const int c  = blockIdx.x;
    const int t  = threadIdx.x;
    const int n0 = cbase[c];
    const int n1 = cbase[c + 1];

    fh[t] = 0; fh[t + 1024] = 0;
    if (t < 64) ldc[t] = 0;
    __syncthreads();

    for (int j = n0 + t; j < n1; j += 1024) {
        const uint32 en = binned[j];
        atomicAdd(&fh[((en >> 24) << 3) | ((en >> 16) & 7)], 1);
    }
    __syncthreads();

    const int a = fh[2 * t], b = fh[2 * t + 1];
    sc[t] = a + b;
    __syncthreads();
    for (int off = 1; off < 1024; off <<= 1) {
        int add = (t >= off) ? sc[t - off] : 0;
        __syncthreads();
        sc[t] += add;
        __syncthreads();
    }
    const int ep = sc[t] - (a + b);
    fex[2 * t] = ep; fex[2 * t + 1] = ep + a;
    __syncthreads();

    fcur[t] = fex[t]; fcur[t + 1024] = fex[t + 1024];
    {
        const int k0 = c << 11;
        start[k0 + t]        = n0 + fex[t];
        start[k0 + t + 1024] = n0 + fex[t + 1024];
    }
    if (c == NC - 1 && t == 0) start[NC << 11] = n1;

    // per-node degree -> LDS degree histogram (fex is stable pre-sync is NOT
    // guaranteed here, but fex was written before the previous __syncthreads).
    if (t < 256) {
        const int node = c * 256 + t;
        if (node < nN) {
            const int lo  = fex[t * 8];
            const int hi  = (t < 255) ? fex[(t + 1) * 8] : (n1 - n0);
            const int deg = hi - lo;
            atomicAdd(&ldc[min(deg, 63)], 1);
        }
    }
    __syncthreads();

    if (t < 64 && ldc[t]) atomicAdd(&dcnt[t], ldc[t]);

    for (int j = n0 + t; j < n1; j += 1024) {
        const uint32 en = binned[j];
        const int fk  = ((en >> 24) << 3) | ((en >> 16) & 7);
        const int off = atomicAdd(&fcur[fk], 1);
        sorted[n0 + off] = (int)(en & 0x7FFFFu);   // (rel<<16)|src
    }
}

// ---------------------------------------------------------------------------
// Exclusive scan of the 64 degree-bucket counts -> dcur.
// ---------------------------------------------------------------------------
__global__ __launch_bounds__(64) void dscan_k(
    const int* __restrict__ dcnt, int* __restrict__ dcur)
{
    __shared__ int sd[64];
    const int t = threadIdx.x;
    const int v = dcnt[t];
    sd[t] = v;
    __syncthreads();
    for (int off = 1; off < 64; off <<= 1) {
        int add = (t >= off) ? sd[t - off] : 0;
        __syncthreads();
        sd[t] += add;
        __syncthreads();
    }
    dcur[t] = sd[t] - v;
}

// ---------------------------------------------------------------------------
// Build degree-sorted node permutation (bin_k pattern, 64 buckets).
// ---------------------------------------------------------------------------
__global__ __launch_bounds__(256) void dperm_k(
    const int* __restrict__ start, int* __restrict__ dcur,
    int* __restrict__ perm, int nN)
{
    __shared__ int lh[64], lb[64], lc[64];
    const int t = threadIdx.x;
    if (t < 64) lh[t] = 0;
    __syncthreads();

    const int base = blockIdx.x * 2048;
    #pragma unroll
    for (int i = 0; i < 8; ++i) {
        const int n = base + t + i * 256;
        if (n < nN) {
            const int deg = start[n * NREL + NREL] - start[n * NREL];
            atomicAdd(&lh[min(deg, 63)], 1);
        }
    }
    __syncthreads();

    if (t < 64) { lb[t] = lh[t] ? atomicAdd(&dcur[t], lh[t]) : 0; lc[t] = 0; }
    __syncthreads();

    #pragma unroll
    for (int i = 0; i < 8; ++i) {
        const int n = base + t + i * 256;
        if (n < nN) {
            const int b   = min(start[n * NREL + NREL] - start[n * NREL], 63);
            const int off = atomicAdd(&lc[b], 1);
            perm[lb[b] + off] = n;
        }
    }
}

// ---------------------------------------------------------------------------
// Fused aggregate + GEMM, v3: block = 16 degree-similar nodes (perm order).
// Phase 1: 16 half-waves, one node each, flat flush-on-rel-change loop into
// XOR-swizzled LDS A-tile. Phase 2: waves 0-3 do the 16-step MFMA col-tiles,
// writing out[] through the perm indirection. C/D layout per m89.
// ---------------------------------------------------------------------------
#define AGG_FLUSH()                                                          \
    {                                                                        \
        const int widx = (row * 256 + (prev * 2 + (l32 >> 4)) * 16 +         \
                          (l32 & 15)) ^ ((row & 7) << 2);                    \
        als[widx] = packbf(a0, a1);                                          \
    }

#define AGG_PROCESS(eu, uu)                                                  \
    {                                                                        \
        const int r_ = (int)((eu) >> 16);                                    \
        if (r_ != prev) {                                                    \
            if (prev >= 0) AGG_FLUSH();                                      \
            a0 = 0.f; a1 = 0.f;                                              \
            prev = r_;                                                       \
        }                                                                    \
        a0 += bflo(uu); a1 += bfhi(uu);                                      \
    }

__global__ __launch_bounds__(512) void aggemm_k(
    const uint32* __restrict__ xbf, const int* __restrict__ start,
    const int* __restrict__ sorted, const int* __restrict__ perm,
    const uint32* __restrict__ Bfrag, float* __restrict__ out, int nN)
{
    __shared__ uint32 als[NPB * 256];   // 16 KB
    __shared__ int    pnode[NPB];

    const int t      = threadIdx.x;
    const int row    = t >> 5;          // half-wave 0..15 = A-tile row
    const int l32    = t & 31;
    const int idx    = blockIdx.x * NPB + row;
    const int n      = (idx < nN) ? perm[idx] : -1;

    if (l32 == 0) pnode[row] = n;

    // zero this row (covers empty rels and tail rows)
    #pragma unroll
    for (int z = 0; z < 8; ++z)
        als[(row * 256 + z * 32 + l32) ^ ((row & 7) << 2)] = 0u;

    if (n >= 0) {
        const int kb = n * NREL;
        const int b0 = start[kb];
        const int b8 = start[kb + 8];

        int   prev = -1;
        float a0 = 0.f, a1 = 0.f;

        int j = b0;
        for (; j + 4 <= b8; j += 4) {
            const uint32 e0 = (uint32)sorted[j];
            const uint32 e1 = (uint32)sorted[j + 1];
            const uint32 e2 = (uint32)sorted[j + 2];
            const uint32 e3 = (uint32)sorted[j + 3];
            const uint32 u0 = xbf[(size_t)(e0 & 0xFFFFu) * 32 + l32];
            const uint32 u1 = xbf[(size_t)(e1 & 0xFFFFu) * 32 + l32];
            const uint32 u2 = xbf[(size_t)(e2 & 0xFFFFu) * 32 + l32];
            const uint32 u3 = xbf[(size_t)(e3 & 0xFFFFu) * 32 + l32];
            AGG_PROCESS(e0, u0);
            AGG_PROCESS(e1, u1);
            AGG_PROCESS(e2, u2);
            AGG_PROCESS(e3, u3);
        }
        for (; j < b8; ++j) {
            const uint32 e = (uint32)sorted[j];
            const uint32 u = xbf[(size_t)(e & 0xFFFFu) * 32 + l32];
            AGG_PROCESS(e, u);
        }
        if (prev >= 0) AGG_FLUSH();
    }
    __syncthreads();

    // ---- phase 2: MFMA (waves 0-3 only) ----
    if (t < 256) {
        const int lane = t & 63;
        const int w    = t >> 6;            // col tile 0..3
        const int rl   = lane & 15;
        const int kq   = lane >> 4;

        f32x4 acc = (f32x4){0.f, 0.f, 0.f, 0.f};
        const uint32* bp = Bfrag + (size_t)lane * 4;

        #pragma unroll
        for (int ks = 0; ks < 16; ++ks) {
            const int aidx = (rl * 256 + ks * 16 + kq * 4) ^ ((rl & 7) << 2);
            U4 ua, ub;
            ua.u = *(const uint4*)(als + aidx);
            ub.u = *(const uint4*)(bp + (size_t)(ks * 4 + w) * 256);
            acc = __builtin_amdgcn_mfma_f32_16x16x32_bf16(ua.v, ub.v, acc, 0, 0, 0);
        }

        #pragma unroll
        for (int reg = 0; reg < 4; ++reg) {
            const int rr = kq * 4 + reg;
            const int nn = pnode[rr];
            if (nn >= 0)
                out[(size_t)nn * 64 + w * 16 + rl] = acc[reg];
        }
    }
}

// ---------------------------------------------------------------------------
// Fallback: per-edge direct with atomics.
// ---------------------------------------------------------------------------
__global__ __launch_bounds__(256) void rgcn_direct_kernel(
    const float* __restrict__ x, const float* __restrict__ W,
    const int* __restrict__ ei, const int* __restrict__ rel,
    float* __restrict__ out, int nE, int nWaves)
{
    const int w    = (int)((blockIdx.x * 256u + threadIdx.x) >> 6);
    const int lane = threadIdx.x & 63;

    for (int e = w; e < nE; e += nWaves) {
        const int src = ei[e];
        const int dst = ei[nE + e];
        const int r   = rel[e];
        const float* xrow = x + (size_t)src * CH;
        const float* wcol = W + ((size_t)r << 12) + lane;
        float acc = 0.f;
        #pragma unroll
        for (int i = 0; i < CH; ++i) acc += xrow[i] * wcol[i * CH];
        atomicAdd(out + (size_t)dst * CH + lane, acc);
    }
}

static inline size_t align256(size_t v) { return (v + 255) & ~(size_t)255; }

extern "C" void kernel_launch(void* const* d_in, const int* in_sizes, int n_in,
                              void* d_out, int out_size, void* d_ws, size_t ws_size,
                              hipStream_t stream) {
    const float* x   = (const float*)d_in[0];
    const float* W   = (const float*)d_in[1];
    const int*   ei  = (const int*)d_in[2];
    const int*   rel = (const int*)d_in[3];
    float*       out = (float*)d_out;

    const int nN  = in_sizes[0] / CH;   // 50000
    const int nE  = in_sizes[3];        // 1000000
    const int NC  = (nN + 255) >> 8;    // 196 coarse buckets
    const int nHB = 256;                // chist blocks

    // Workspace layout
    const size_t sz_xbf    = align256((size_t)nN * 32 * sizeof(uint32));        // 6.4 MB
    const size_t sz_start  = align256(((size_t)NC * 2048 + 2) * sizeof(int));   // 1.6 MB
    const size_t sz_binned = align256((size_t)nE * sizeof(uint32));             // 4 MB
    const size_t sz_sorted = align256((size_t)nE * sizeof(int));                // 4 MB
    const size_t sz_bfrag  = align256((size_t)16384 * sizeof(uint32));          // 64 KB
    const size_t sz_cpart  = align256((size_t)nHB * 256 * sizeof(int));         // 256 KB
    const size_t sz_cbase  = align256(257 * sizeof(int));
    const size_t sz_ccur   = align256(256 * sizeof(int));
    const size_t sz_perm   = align256((size_t)nN * sizeof(int));                // 200 KB
    const size_t sz_dcnt   = align256(64 * sizeof(int));
    const size_t sz_dcur   = align256(64 * sizeof(int));
    const size_t need = sz_xbf + sz_start + sz_binned + sz_sorted + sz_bfrag +
                        sz_cpart + sz_cbase + sz_ccur + sz_perm + sz_dcnt + sz_dcur;

    if (ws_size >= need && nN <= 65024 && NC <= 254) {
        char* p = (char*)d_ws;
        uint32* xbf    = (uint32*)p;  p += sz_xbf;
        int*    start  = (int*)p;     p += sz_start;
        uint32* binned = (uint32*)p;  p += sz_binned;
        int*    sorted = (int*)p;     p += sz_sorted;
        uint32* Bfrag  = (uint32*)p;  p += sz_bfrag;
        int*    cpart  = (int*)p;     p += sz_cpart;
        int*    cbase  = (int*)p;     p += sz_cbase;
        int*    ccur   = (int*)p;     p += sz_ccur;
        int*    perm   = (int*)p;     p += sz_perm;
        int*    dcnt   = (int*)p;     p += sz_dcnt;
        int*    dcur   = (int*)p;

        hipMemsetAsync(dcnt, 0, 64 * sizeof(int), stream);

        const int n2 = nN * 32;
        prep_k<<<16 + (n2 + 255) / 256, 256, 0, stream>>>(x, xbf, W, Bfrag, n2);

        chist_k<<<nHB, 256, 0, stream>>>(ei, cpart, nE, nHB * 256);
        cscan_k<<<1, 256, 0, stream>>>(cpart, cbase, ccur, NC, nHB);
        bin_k<<<(nE + 2047) / 2048, 256, 0, stream>>>(ei, rel, ccur, binned, nE);
        fsort_k<<<NC, 1024, 0, stream>>>(binned, cbase, start, sorted, dcnt, NC, nN);

        dscan_k<<<1, 64, 0, stream>>>(dcnt, dcur);
        dperm_k<<<(nN + 2047) / 2048, 256, 0, stream>>>(start, dcur, perm, nN);

        aggemm_k<<<(nN + NPB - 1) / NPB, 512, 0, stream>>>(
            xbf, start, sorted, perm, Bfrag, out, nN);
    } else {
        hipMemsetAsync(out, 0, (size_t)out_size * sizeof(float), stream);
        const int blocks = 2048;
        const int nWaves = blocks * (256 / 64);
        rgcn_direct_kernel<<<blocks, 256, 0, stream>>>(x, W, ei, rel, out, nE, nWaves);
    }
}

// Round 13
// 132.721 us; speedup vs baseline: 1.0161x; 1.0161x over previous
//
#include <hip/hip_runtime.h>
#include <hip/hip_bf16.h>

#define NREL 8
#define CH   64   // IN_CH == HID_CH == 64

typedef unsigned int uint32;
typedef __attribute__((ext_vector_type(8))) short bf16x8;
typedef __attribute__((ext_vector_type(4))) float f32x4;
union U4 { uint4 u; bf16x8 v; };

// ---- bf16 helpers (RNE) ----------------------------------------------------
static __device__ __forceinline__ uint32 packbf(float a, float b) {
    uint32 ua = __float_as_uint(a), ub = __float_as_uint(b);
    ua = (ua + 0x7fffu + ((ua >> 16) & 1u)) >> 16;          // low half  (elem 0 = even k)
    ub = (ub + 0x7fffu + ((ub >> 16) & 1u)) & 0xffff0000u;  // high half (elem 1 = odd k)
    return ua | ub;
}
static __device__ __forceinline__ float bflo(uint32 w) { return __uint_as_float(w << 16); }
static __device__ __forceinline__ float bfhi(uint32 w) { return __uint_as_float(w & 0xffff0000u); }

// ---------------------------------------------------------------------------
// prep: blocks [0,16) build B-fragments from W; the rest pack x into bf16.
// Bfrag[((ks*4+c)*64+lane)*4 + j2] = packed W[ks*32+(lane>>4)*8+2j2..+1][c*16+(lane&15)]
// (same lane->k mapping as the A side, so any k-permutation cancels).
// ---------------------------------------------------------------------------
__global__ __launch_bounds__(256) void prep_k(
    const float* __restrict__ x, uint32* __restrict__ xbf,
    const float* __restrict__ Wf, uint32* __restrict__ Bfrag, int n2)
{
    if (blockIdx.x < 16) {
        const int idx  = blockIdx.x * 256 + threadIdx.x;   // 0..4095
        const int lane = idx & 63;
        const int c    = (idx >> 6) & 3;
        const int ks   = idx >> 8;                          // 0..15
        const int col  = c * 16 + (lane & 15);
        const int k0   = ks * 32 + (lane >> 4) * 8;
        uint4 o;
        o.x = packbf(Wf[(k0 + 0) * 64 + col], Wf[(k0 + 1) * 64 + col]);
        o.y = packbf(Wf[(k0 + 2) * 64 + col], Wf[(k0 + 3) * 64 + col]);
        o.z = packbf(Wf[(k0 + 4) * 64 + col], Wf[(k0 + 5) * 64 + col]);
        o.w = packbf(Wf[(k0 + 6) * 64 + col], Wf[(k0 + 7) * 64 + col]);
        *(uint4*)(Bfrag + (size_t)idx * 4) = o;
    } else {
        const int i = (blockIdx.x - 16) * 256 + threadIdx.x;
        if (i < n2) {
            const float2 v = ((const float2*)x)[i];
            xbf[i] = packbf(v.x, v.y);
        }
    }
}

// ---------------------------------------------------------------------------
// Coarse histogram over c = dst>>8: per-block partials (no global atomics).
// ---------------------------------------------------------------------------
__global__ __launch_bounds__(256) void chist_k(
    const int* __restrict__ ei, int* __restrict__ cpart, int nE, int nT)
{
    __shared__ int h[256];
    h[threadIdx.x] = 0;
    __syncthreads();
    for (int e = blockIdx.x * 256 + threadIdx.x; e < nE; e += nT)
        atomicAdd(&h[ei[nE + e] >> 8], 1);
    __syncthreads();
    cpart[blockIdx.x * 256 + threadIdx.x] = h[threadIdx.x];
}

// ---------------------------------------------------------------------------
// Column-sum partials + exclusive scan -> cbase[0..NC], ccur.
// ---------------------------------------------------------------------------
__global__ __launch_bounds__(256) void cscan_k(
    const int* __restrict__ cpart, int* __restrict__ cbase,
    int* __restrict__ ccur, int NC, int nHB)
{
    __shared__ int sc[256];
    const int t = threadIdx.x;
    int v = 0;
    for (int b = 0; b < nHB; ++b) v += cpart[b * 256 + t];
    sc[t] = v;
    __syncthreads();
    for (int off = 1; off < 256; off <<= 1) {
        int add = (t >= off) ? sc[t - off] : 0;
        __syncthreads();
        sc[t] += add;
        __syncthreads();
    }
    const int ex = sc[t] - v;
    if (t < NC) { cbase[t] = ex; ccur[t] = ex; }
    if (t == 255) cbase[NC] = sc[255];
}

// ---------------------------------------------------------------------------
// Coarse binning: per 2048-edge chunk, stage in LDS, reserve runs, write runs.
// Entry pack: (dlow<<24)|(rel<<16)|src.
// ---------------------------------------------------------------------------
__global__ __launch_bounds__(256) void bin_k(
    const int* __restrict__ ei, const int* __restrict__ rel,
    int* __restrict__ ccur, uint32* __restrict__ binned, int nE)
{
    __shared__ uint32        ent[2048];
    __shared__ unsigned char cid[2048];
    __shared__ int lh[256], lb[256], lc[256];

    const int t = threadIdx.x;
    lh[t] = 0;
    __syncthreads();

    const int base = blockIdx.x * 2048;
    #pragma unroll
    for (int i = 0; i < 8; ++i) {
        const int idx = t + i * 256;
        const int e   = base + idx;
        if (e < nE) {
            const int dst = ei[nE + e];
            ent[idx] = ((uint32)(dst & 255) << 24) | ((uint32)rel[e] << 16) | (uint32)ei[e];
            const int c = dst >> 8;
            cid[idx] = (unsigned char)c;
            atomicAdd(&lh[c], 1);
        } else {
            cid[idx] = 255;   // sentinel (NC <= 254 guard in launcher)
        }
    }
    __syncthreads();

    if (lh[t]) lb[t] = atomicAdd(&ccur[t], lh[t]);
    lc[t] = 0;
    __syncthreads();

    #pragma unroll
    for (int i = 0; i < 8; ++i) {
        const int idx = t + i * 256;
        const int c   = cid[idx];
        if (c != 255) {
            const int off = atomicAdd(&lc[c], 1);
            binned[lb[c] + off] = ent[idx];
        }
    }
}

// ---------------------------------------------------------------------------
// Fine sort within one coarse bucket (keyspace 2048 = dlow*8+rel), in LDS.
// sorted[] keeps (rel<<16)|src for flush-on-rel-change aggregation.
// ---------------------------------------------------------------------------
__global__ __launch_bounds__(1024) void fsort_k(
    const uint32* __restrict__ binned, const int* __restrict__ cbase,
    int* __restrict__ start, int* __restrict__ sorted, int NC)
{
    __shared__ int fh[2048], fex[2048], fcur[2048], sc[1024];
    const int c  = blockIdx.x;
    const int t  = threadIdx.x;
    const int n0 = cbase[c];
    const int n1 = cbase[c + 1];

    fh[t] = 0; fh[t + 1024] = 0;
    __syncthreads();

    for (int j = n0 + t; j < n1; j += 1024) {
        const uint32 en = binned[j];
        atomicAdd(&fh[((en >> 24) << 3) | ((en >> 16) & 7)], 1);
    }
    __syncthreads();

    const int a = fh[2 * t], b = fh[2 * t + 1];
    sc[t] = a + b;
    __syncthreads();
    for (int off = 1; off < 1024; off <<= 1) {
        int add = (t >= off) ? sc[t - off] : 0;
        __syncthreads();
        sc[t] += add;
        __syncthreads();
    }
    const int ep = sc[t] - (a + b);
    fex[2 * t] = ep; fex[2 * t + 1] = ep + a;
    __syncthreads();

    fcur[t] = fex[t]; fcur[t + 1024] = fex[t + 1024];
    {
        const int k0 = c << 11;
        start[k0 + t]        = n0 + fex[t];
        start[k0 + t + 1024] = n0 + fex[t + 1024];
    }
    if (c == NC - 1 && t == 0) start[NC << 11] = n1;
    __syncthreads();

    for (int j = n0 + t; j < n1; j += 1024) {
        const uint32 en = binned[j];
        const int fk  = ((en >> 24) << 3) | ((en >> 16) & 7);
        const int off = atomicAdd(&fcur[fk], 1);
        sorted[n0 + off] = (int)(en & 0x7FFFFu);   // (rel<<16)|src
    }
}

// ---------------------------------------------------------------------------
// Aggregate: one HALF-WAVE per dst node, flat 4-unrolled flush-on-rel-change
// loop (r8/r9-verified). lane%32 = channel pair.
// ---------------------------------------------------------------------------
#define AGG_PROCESS(eu, uu)                                            \
    {                                                                  \
        const int r_ = (int)((eu) >> 16);                              \
        if (r_ != prev) {                                              \
            if (prev >= 0)                                             \
                A[(size_t)(kb + prev) * 32 + l32] = packbf(a0, a1);    \
            a0 = 0.f; a1 = 0.f;                                        \
            prev = r_;                                                 \
            seen |= (1u << r_);                                        \
        }                                                              \
        a0 += bflo(uu); a1 += bfhi(uu);                                \
    }

__global__ __launch_bounds__(256) void agg_k(
    const uint32* __restrict__ xbf, const int* __restrict__ start,
    const int* __restrict__ sorted, uint32* __restrict__ A, int nN)
{
    const int n = (int)((blockIdx.x * 256u + threadIdx.x) >> 5);   // half-wave id
    if (n >= nN) return;
    const int l32 = threadIdx.x & 31;
    const int kb  = n * NREL;

    const int b0 = start[kb];
    const int b8 = start[kb + 8];

    int   prev = -1;
    float a0 = 0.f, a1 = 0.f;
    unsigned seen = 0;

    int j = b0;
    for (; j + 4 <= b8; j += 4) {
        const uint32 e0 = (uint32)sorted[j];
        const uint32 e1 = (uint32)sorted[j + 1];
        const uint32 e2 = (uint32)sorted[j + 2];
        const uint32 e3 = (uint32)sorted[j + 3];
        const uint32 u0 = xbf[(size_t)(e0 & 0xFFFFu) * 32 + l32];
        const uint32 u1 = xbf[(size_t)(e1 & 0xFFFFu) * 32 + l32];
        const uint32 u2 = xbf[(size_t)(e2 & 0xFFFFu) * 32 + l32];
        const uint32 u3 = xbf[(size_t)(e3 & 0xFFFFu) * 32 + l32];
        AGG_PROCESS(e0, u0);
        AGG_PROCESS(e1, u1);
        AGG_PROCESS(e2, u2);
        AGG_PROCESS(e3, u3);
    }
    for (; j < b8; ++j) {
        const uint32 e = (uint32)sorted[j];
        const uint32 u = xbf[(size_t)(e & 0xFFFFu) * 32 + l32];
        AGG_PROCESS(e, u);
    }

    if (prev >= 0)
        A[(size_t)(kb + prev) * 32 + l32] = packbf(a0, a1);

    #pragma unroll
    for (int r = 0; r < NREL; ++r)
        if (!(seen & (1u << r)))
            A[(size_t)(kb + r) * 32 + l32] = 0u;
}

// ---------------------------------------------------------------------------
// GEMM (MFMA, r9-verified): out[nN,64] = A[nN,512](bf16) @ W(bf16 frags).
// One wave per 32 rows (two 16-row tiles x 4 col-tiles), no LDS, no barriers.
// C/D layout per m89: col=lane&15, row=(lane>>4)*4+reg.
// ---------------------------------------------------------------------------
__global__ __launch_bounds__(256) void gemm_k(
    const uint32* __restrict__ A, const uint32* __restrict__ Bfrag,
    float* __restrict__ out, int nN)
{
    const int wv   = (int)((blockIdx.x * 256u + threadIdx.x) >> 6);
    const int lane = threadIdx.x & 63;
    const int n0   = wv * 32;
    if (n0 >= nN) return;

    const int rl = lane & 15;
    const int kq = lane >> 4;

    int r0 = n0 + rl;      if (r0 >= nN) r0 = nN - 1;
    int r1 = n0 + 16 + rl; if (r1 >= nN) r1 = nN - 1;
    const uint32* a0p = A + (size_t)r0 * 256 + kq * 4;
    const uint32* a1p = A + (size_t)r1 * 256 + kq * 4;
    const uint32* bp  = Bfrag + (size_t)lane * 4;

    f32x4 acc[2][4];
    #pragma unroll
    for (int t = 0; t < 2; ++t)
        #pragma unroll
        for (int c = 0; c < 4; ++c)
            acc[t][c] = (f32x4){0.f, 0.f, 0.f, 0.f};

    #pragma unroll 4
    for (int ks = 0; ks < 16; ++ks) {
        U4 ua0, ua1;
        ua0.u = *(const uint4*)(a0p + ks * 16);
        ua1.u = *(const uint4*)(a1p + ks * 16);
        #pragma unroll
        for (int c = 0; c < 4; ++c) {
            U4 ub;
            ub.u = *(const uint4*)(bp + ((size_t)(ks * 4 + c)) * 256);
            acc[0][c] = __builtin_amdgcn_mfma_f32_16x16x32_bf16(ua0.v, ub.v, acc[0][c], 0, 0, 0);
            acc[1][c] = __builtin_amdgcn_mfma_f32_16x16x32_bf16(ua1.v, ub.v, acc[1][c], 0, 0, 0);
        }
    }

    #pragma unroll
    for (int t = 0; t < 2; ++t)
        #pragma unroll
        for (int c = 0; c < 4; ++c)
            #pragma unroll
            for (int reg = 0; reg < 4; ++reg) {
                const int row = n0 + t * 16 + kq * 4 + reg;
                if (row < nN)
                    out[(size_t)row * 64 + c * 16 + rl] = acc[t][c][reg];
            }
}

// ---------------------------------------------------------------------------
// Fallback: per-edge direct with atomics.
// ---------------------------------------------------------------------------
__global__ __launch_bounds__(256) void rgcn_direct_kernel(
    const float* __restrict__ x, const float* __restrict__ W,
    const int* __restrict__ ei, const int* __restrict__ rel,
    float* __restrict__ out, int nE, int nWaves)
{
    const int w    = (int)((blockIdx.x * 256u + threadIdx.x) >> 6);
    const int lane = threadIdx.x & 63;

    for (int e = w; e < nE; e += nWaves) {
        const int src = ei[e];
        const int dst = ei[nE + e];
        const int r   = rel[e];
        const float* xrow = x + (size_t)src * CH;
        const float* wcol = W + ((size_t)r << 12) + lane;
        float acc = 0.f;
        #pragma unroll
        for (int i = 0; i < CH; ++i) acc += xrow[i] * wcol[i * CH];
        atomicAdd(out + (size_t)dst * CH + lane, acc);
    }
}

static inline size_t align256(size_t v) { return (v + 255) & ~(size_t)255; }

extern "C" void kernel_launch(void* const* d_in, const int* in_sizes, int n_in,
                              void* d_out, int out_size, void* d_ws, size_t ws_size,
                              hipStream_t stream) {
    const float* x   = (const float*)d_in[0];
    const float* W   = (const float*)d_in[1];
    const int*   ei  = (const int*)d_in[2];
    const int*   rel = (const int*)d_in[3];
    float*       out = (float*)d_out;

    const int nN  = in_sizes[0] / CH;   // 50000
    const int nE  = in_sizes[3];        // 1000000
    const int nK  = nN * NREL;          // 400000
    const int NC  = (nN + 255) >> 8;    // 196 coarse buckets
    const int nHB = 256;                // chist blocks

    // Workspace layout
    const size_t sz_A      = align256((size_t)nK * 32 * sizeof(uint32));        // 51.2 MB
    const size_t sz_xbf    = align256((size_t)nN * 32 * sizeof(uint32));        // 6.4 MB
    const size_t sz_start  = align256(((size_t)NC * 2048 + 2) * sizeof(int));   // 1.6 MB
    const size_t sz_binned = align256((size_t)nE * sizeof(uint32));             // 4 MB
    const size_t sz_sorted = align256((size_t)nE * sizeof(int));                // 4 MB
    const size_t sz_bfrag  = align256((size_t)16384 * sizeof(uint32));          // 64 KB
    const size_t sz_cpart  = align256((size_t)nHB * 256 * sizeof(int));         // 256 KB
    const size_t sz_cbase  = align256(257 * sizeof(int));
    const size_t sz_ccur   = align256(256 * sizeof(int));
    const size_t need = sz_A + sz_xbf + sz_start + sz_binned + sz_sorted +
                        sz_bfrag + sz_cpart + sz_cbase + sz_ccur;

    if (ws_size >= need && nN <= 65024 && NC <= 254) {
        char* p = (char*)d_ws;
        uint32* A      = (uint32*)p;  p += sz_A;
        uint32* xbf    = (uint32*)p;  p += sz_xbf;
        int*    start  = (int*)p;     p += sz_start;
        uint32* binned = (uint32*)p;  p += sz_binned;
        int*    sorted = (int*)p;     p += sz_sorted;
        uint32* Bfrag  = (uint32*)p;  p += sz_bfrag;
        int*    cpart  = (int*)p;     p += sz_cpart;
        int*    cbase  = (int*)p;     p += sz_cbase;
        int*    ccur   = (int*)p;

        const int n2 = nN * 32;
        prep_k<<<16 + (n2 + 255) / 256, 256, 0, stream>>>(x, xbf, W, Bfrag, n2);

        chist_k<<<nHB, 256, 0, stream>>>(ei, cpart, nE, nHB * 256);
        cscan_k<<<1, 256, 0, stream>>>(cpart, cbase, ccur, NC, nHB);
        bin_k<<<(nE + 2047) / 2048, 256, 0, stream>>>(ei, rel, ccur, binned, nE);
        fsort_k<<<NC, 1024, 0, stream>>>(binned, cbase, start, sorted, NC);

        const int aggBlocks = (nN + 7) / 8;    // one half-wave per node
        agg_k<<<aggBlocks, 256, 0, stream>>>(xbf, start, sorted, A, nN);

        const int gemmWaves  = (nN + 31) / 32;
        const int gemmBlocks = (gemmWaves + 3) / 4;
        gemm_k<<<gemmBlocks, 256, 0, stream>>>(A, Bfrag, out, nN);
    } else {
        hipMemsetAsync(out, 0, (size_t)out_size * sizeof(float), stream);
        const int blocks = 2048;
        const int nWaves = blocks * (256 / 64);
        rgcn_direct_kernel<<<blocks, 256, 0, stream>>>(x, W, ei, rel, out, nE, nWaves);
    }
}

// Round 14
// 97.114 us; speedup vs baseline: 1.3886x; 1.3667x over previous
//
#include <hip/hip_runtime.h>
#include <hip/hip_bf16.h>

#define NREL 8
#define CH   64   // IN_CH == HID_CH == 64
#define NPB  16   // nodes per block in fused agg+gemm

typedef unsigned int uint32;
typedef __attribute__((ext_vector_type(8))) short bf16x8;
typedef __attribute__((ext_vector_type(4))) float f32x4;
union U4 { uint4 u; bf16x8 v; };

// ---- bf16 helpers (RNE) ----------------------------------------------------
static __device__ __forceinline__ uint32 packbf(float a, float b) {
    uint32 ua = __float_as_uint(a), ub = __float_as_uint(b);
    ua = (ua + 0x7fffu + ((ua >> 16) & 1u)) >> 16;          // low half  (elem 0 = even k)
    ub = (ub + 0x7fffu + ((ub >> 16) & 1u)) & 0xffff0000u;  // high half (elem 1 = odd k)
    return ua | ub;
}
static __device__ __forceinline__ float bflo(uint32 w) { return __uint_as_float(w << 16); }
static __device__ __forceinline__ float bfhi(uint32 w) { return __uint_as_float(w & 0xffff0000u); }

// ---------------------------------------------------------------------------
// xbf[n][cp] = packed bf16 pair of x[n][2cp..2cp+1]  (cp = 0..31)   [r9]
// ---------------------------------------------------------------------------
__global__ __launch_bounds__(256) void xbf_k(
    const float* __restrict__ x, uint32* __restrict__ xbf, int n2)
{
    const int i = blockIdx.x * 256 + threadIdx.x;
    if (i < n2) {
        const float2 v = ((const float2*)x)[i];
        xbf[i] = packbf(v.x, v.y);
    }
}

// ---------------------------------------------------------------------------
// B-fragment prep [r9]: Bfrag[((ks*4+c)*64+lane)*4 + j2] packs
// W[ks*32+(lane>>4)*8+2j2 .. +1][c*16+(lane&15)] as bf16 pair.
// Same lane->k mapping as the A side, so any k-permutation cancels.
// ---------------------------------------------------------------------------
__global__ __launch_bounds__(256) void bprep_k(
    const float* __restrict__ Wf, uint32* __restrict__ Bfrag)
{
    const int idx  = blockIdx.x * 256 + threadIdx.x;   // 0..4095
    const int lane = idx & 63;
    const int c    = (idx >> 6) & 3;
    const int ks   = idx >> 8;                          // 0..15
    const int col  = c * 16 + (lane & 15);
    const int k0   = ks * 32 + (lane >> 4) * 8;

    uint4 o;
    o.x = packbf(Wf[(k0 + 0) * 64 + col], Wf[(k0 + 1) * 64 + col]);
    o.y = packbf(Wf[(k0 + 2) * 64 + col], Wf[(k0 + 3) * 64 + col]);
    o.z = packbf(Wf[(k0 + 4) * 64 + col], Wf[(k0 + 5) * 64 + col]);
    o.w = packbf(Wf[(k0 + 6) * 64 + col], Wf[(k0 + 7) * 64 + col]);
    *(uint4*)(Bfrag + (size_t)idx * 4) = o;
}

// ---------------------------------------------------------------------------
// Coarse histogram over c = dst>>8 (NC buckets). LDS-staged atomics [r9].
// ---------------------------------------------------------------------------
__global__ __launch_bounds__(256) void chist_k(
    const int* __restrict__ ei, int* __restrict__ ccnt, int nE, int nT)
{
    __shared__ int h[256];
    h[threadIdx.x] = 0;
    __syncthreads();
    for (int e = blockIdx.x * 256 + threadIdx.x; e < nE; e += nT)
        atomicAdd(&h[ei[nE + e] >> 8], 1);
    __syncthreads();
    const int c = threadIdx.x;
    if (h[c]) atomicAdd(&ccnt[c], h[c]);
}

// ---------------------------------------------------------------------------
// Coarse exclusive scan (NC <= 256), fills cbase[0..NC] and ccur [r9].
// ---------------------------------------------------------------------------
__global__ __launch_bounds__(256) void cscan_k(
    const int* __restrict__ ccnt, int* __restrict__ cbase,
    int* __restrict__ ccur, int NC)
{
    __shared__ int sc[256];
    const int t = threadIdx.x;
    const int v = (t < NC) ? ccnt[t] : 0;
    sc[t] = v;
    __syncthreads();
    for (int off = 1; off < 256; off <<= 1) {
        int add = (t >= off) ? sc[t - off] : 0;
        __syncthreads();
        sc[t] += add;
        __syncthreads();
    }
    const int ex = sc[t] - v;
    if (t < NC) { cbase[t] = ex; ccur[t] = ex; }
    if (t == 255) cbase[NC] = sc[255];
}

// ---------------------------------------------------------------------------
// Coarse binning [r9]: per 2048-edge chunk, stage in LDS, reserve runs, write.
// Entry pack: (dlow<<24)|(rel<<16)|src.
// ---------------------------------------------------------------------------
__global__ __launch_bounds__(256) void bin_k(
    const int* __restrict__ ei, const int* __restrict__ rel,
    int* __restrict__ ccur, uint32* __restrict__ binned, int nE)
{
    __shared__ uint32        ent[2048];
    __shared__ unsigned char cid[2048];
    __shared__ int lh[256], lb[256], lc[256];

    const int t = threadIdx.x;
    lh[t] = 0;
    __syncthreads();

    const int base = blockIdx.x * 2048;
    #pragma unroll
    for (int i = 0; i < 8; ++i) {
        const int idx = t + i * 256;
        const int e   = base + idx;
        if (e < nE) {
            const int dst = ei[nE + e];
            ent[idx] = ((uint32)(dst & 255) << 24) | ((uint32)rel[e] << 16) | (uint32)ei[e];
            const int c = dst >> 8;
            cid[idx] = (unsigned char)c;
            atomicAdd(&lh[c], 1);
        } else {
            cid[idx] = 255;   // sentinel (NC <= 254 guard in launcher)
        }
    }
    __syncthreads();

    if (lh[t]) lb[t] = atomicAdd(&ccur[t], lh[t]);
    lc[t] = 0;
    __syncthreads();

    #pragma unroll
    for (int i = 0; i < 8; ++i) {
        const int idx = t + i * 256;
        const int c   = cid[idx];
        if (c != 255) {
            const int off = atomicAdd(&lc[c], 1);
            binned[lb[c] + off] = ent[idx];
        }
    }
}

// ---------------------------------------------------------------------------
// Fine sort within one coarse bucket (keyspace 2048 = dlow*8+rel), in LDS [r9].
// sorted[] keeps (rel<<16)|src for flush-on-rel-change aggregation.
// ---------------------------------------------------------------------------
__global__ __launch_bounds__(1024) void fsort_k(
    const uint32* __restrict__ binned, const int* __restrict__ cbase,
    int* __restrict__ start, int* __restrict__ sorted, int NC)
{
    __shared__ int fh[2048], fex[2048], fcur[2048], sc[1024];
    const int c  = blockIdx.x;
    const int t  = threadIdx.x;
    const int n0 = cbase[c];
    const int n1 = cbase[c + 1];

    fh[t] = 0; fh[t + 1024] = 0;
    __syncthreads();

    for (int j = n0 + t; j < n1; j += 1024) {
        const uint32 en = binned[j];
        atomicAdd(&fh[((en >> 24) << 3) | ((en >> 16) & 7)], 1);
    }
    __syncthreads();

    const int a = fh[2 * t], b = fh[2 * t + 1];
    sc[t] = a + b;
    __syncthreads();
    for (int off = 1; off < 1024; off <<= 1) {
        int add = (t >= off) ? sc[t - off] : 0;
        __syncthreads();
        sc[t] += add;
        __syncthreads();
    }
    const int ep = sc[t] - (a + b);
    fex[2 * t] = ep; fex[2 * t + 1] = ep + a;
    __syncthreads();

    fcur[t] = fex[t]; fcur[t + 1024] = fex[t + 1024];
    {
        const int k0 = c << 11;
        start[k0 + t]        = n0 + fex[t];
        start[k0 + t + 1024] = n0 + fex[t + 1024];
    }
    if (c == NC - 1 && t == 0) start[NC << 11] = n1;
    __syncthreads();

    for (int j = n0 + t; j < n1; j += 1024) {
        const uint32 en = binned[j];
        const int fk  = ((en >> 24) << 3) | ((en >> 16) & 7);
        const int off = atomicAdd(&fcur[fk], 1);
        sorted[n0 + off] = (int)(en & 0x7FFFFu);   // (rel<<16)|src
    }
}

// ---------------------------------------------------------------------------
// Fused aggregate + GEMM [r11-verified]. Block = 512 threads = 16 half-waves,
// ONE node per half-wave (flat flush-on-rel-change loop), flushing A-frags
// into an XOR-swizzled LDS tile; one barrier; waves 0-3 run the 16-step MFMA
// col-tiles. C/D layout per m89: col=lane&15, row=(lane>>4)*4+reg.
// ---------------------------------------------------------------------------
#define AGG_FLUSH()                                                          \
    {                                                                        \
        const int widx = (row * 256 + (prev * 2 + (l32 >> 4)) * 16 +         \
                          (l32 & 15)) ^ ((row & 7) << 2);                    \
        als[widx] = packbf(a0, a1);                                          \
    }

#define AGG_PROCESS(eu, uu)                                                  \
    {                                                                        \
        const int r_ = (int)((eu) >> 16);                                    \
        if (r_ != prev) {                                                    \
            if (prev >= 0) AGG_FLUSH();                                      \
            a0 = 0.f; a1 = 0.f;                                              \
            prev = r_;                                                       \
        }                                                                    \
        a0 += bflo(uu); a1 += bfhi(uu);                                      \
    }

__global__ __launch_bounds__(512) void aggemm_k(
    const uint32* __restrict__ xbf, const int* __restrict__ start,
    const int* __restrict__ sorted, const uint32* __restrict__ Bfrag,
    float* __restrict__ out, int nN)
{
    __shared__ uint32 als[NPB * 256];   // 16 KB

    const int t      = threadIdx.x;
    const int row    = t >> 5;          // half-wave 0..15 = node row
    const int l32    = t & 31;
    const int n_base = blockIdx.x * NPB;
    const int n      = n_base + row;

    // ---- phase 1: aggregation (one node per half-wave) ----
    #pragma unroll
    for (int z = 0; z < 8; ++z)
        als[(row * 256 + z * 32 + l32) ^ ((row & 7) << 2)] = 0u;

    if (n < nN) {
        const int kb = n * NREL;
        const int b0 = start[kb];
        const int b8 = start[kb + 8];

        int   prev = -1;
        float a0 = 0.f, a1 = 0.f;

        int j = b0;
        for (; j + 4 <= b8; j += 4) {
            const uint32 e0 = (uint32)sorted[j];
            const uint32 e1 = (uint32)sorted[j + 1];
            const uint32 e2 = (uint32)sorted[j + 2];
            const uint32 e3 = (uint32)sorted[j + 3];
            const uint32 u0 = xbf[(size_t)(e0 & 0xFFFFu) * 32 + l32];
            const uint32 u1 = xbf[(size_t)(e1 & 0xFFFFu) * 32 + l32];
            const uint32 u2 = xbf[(size_t)(e2 & 0xFFFFu) * 32 + l32];
            const uint32 u3 = xbf[(size_t)(e3 & 0xFFFFu) * 32 + l32];
            AGG_PROCESS(e0, u0);
            AGG_PROCESS(e1, u1);
            AGG_PROCESS(e2, u2);
            AGG_PROCESS(e3, u3);
        }
        for (; j < b8; ++j) {
            const uint32 e = (uint32)sorted[j];
            const uint32 u = xbf[(size_t)(e & 0xFFFFu) * 32 + l32];
            AGG_PROCESS(e, u);
        }
        if (prev >= 0) AGG_FLUSH();
    }
    __syncthreads();

    // ---- phase 2: MFMA (waves 0-3 only) ----
    if (t < 256) {
        const int lane = t & 63;
        const int w    = t >> 6;            // col tile 0..3
        const int rl   = lane & 15;
        const int kq   = lane >> 4;

        f32x4 acc = (f32x4){0.f, 0.f, 0.f, 0.f};
        const uint32* bp = Bfrag + (size_t)lane * 4;

        #pragma unroll
        for (int ks = 0; ks < 16; ++ks) {
            const int aidx = (rl * 256 + ks * 16 + kq * 4) ^ ((rl & 7) << 2);
            U4 ua, ub;
            ua.u = *(const uint4*)(als + aidx);
            ub.u = *(const uint4*)(bp + (size_t)(ks * 4 + w) * 256);
            acc = __builtin_amdgcn_mfma_f32_16x16x32_bf16(ua.v, ub.v, acc, 0, 0, 0);
        }

        #pragma unroll
        for (int reg = 0; reg < 4; ++reg) {
            const int rr = kq * 4 + reg;
            const int nn = n_base + rr;
            if (nn < nN)
                out[(size_t)nn * 64 + w * 16 + rl] = acc[reg];
        }
    }
}

// ---------------------------------------------------------------------------
// Fallback: per-edge direct with atomics.
// ---------------------------------------------------------------------------
__global__ __launch_bounds__(256) void rgcn_direct_kernel(
    const float* __restrict__ x, const float* __restrict__ W,
    const int* __restrict__ ei, const int* __restrict__ rel,
    float* __restrict__ out, int nE, int nWaves)
{
    const int w    = (int)((blockIdx.x * 256u + threadIdx.x) >> 6);
    const int lane = threadIdx.x & 63;

    for (int e = w; e < nE; e += nWaves) {
        const int src = ei[e];
        const int dst = ei[nE + e];
        const int r   = rel[e];
        const float* xrow = x + (size_t)src * CH;
        const float* wcol = W + ((size_t)r << 12) + lane;
        float acc = 0.f;
        #pragma unroll
        for (int i = 0; i < CH; ++i) acc += xrow[i] * wcol[i * CH];
        atomicAdd(out + (size_t)dst * CH + lane, acc);
    }
}

static inline size_t align256(size_t v) { return (v + 255) & ~(size_t)255; }

extern "C" void kernel_launch(void* const* d_in, const int* in_sizes, int n_in,
                              void* d_out, int out_size, void* d_ws, size_t ws_size,
                              hipStream_t stream) {
    const float* x   = (const float*)d_in[0];
    const float* W   = (const float*)d_in[1];
    const int*   ei  = (const int*)d_in[2];
    const int*   rel = (const int*)d_in[3];
    float*       out = (float*)d_out;

    const int nN = in_sizes[0] / CH;   // 50000
    const int nE = in_sizes[3];        // 1000000
    const int NC = (nN + 255) >> 8;    // 196 coarse buckets

    // Workspace layout
    const size_t sz_xbf    = align256((size_t)nN * 32 * sizeof(uint32));        // 6.4 MB
    const size_t sz_start  = align256(((size_t)NC * 2048 + 2) * sizeof(int));   // 1.6 MB
    const size_t sz_binned = align256((size_t)nE * sizeof(uint32));             // 4 MB
    const size_t sz_sorted = align256((size_t)nE * sizeof(int));                // 4 MB
    const size_t sz_bfrag  = align256((size_t)16384 * sizeof(uint32));          // 64 KB
    const size_t sz_ccnt   = align256(256 * sizeof(int));
    const size_t sz_cbase  = align256(257 * sizeof(int));
    const size_t sz_ccur   = align256(256 * sizeof(int));
    const size_t need = sz_xbf + sz_start + sz_binned + sz_sorted +
                        sz_bfrag + sz_ccnt + sz_cbase + sz_ccur;

    if (ws_size >= need && nN <= 65024 && NC <= 254) {
        char* p = (char*)d_ws;
        uint32* xbf    = (uint32*)p;  p += sz_xbf;
        int*    start  = (int*)p;     p += sz_start;
        uint32* binned = (uint32*)p;  p += sz_binned;
        int*    sorted = (int*)p;     p += sz_sorted;
        uint32* Bfrag  = (uint32*)p;  p += sz_bfrag;
        int*    ccnt   = (int*)p;     p += sz_ccnt;
        int*    cbase  = (int*)p;     p += sz_cbase;
        int*    ccur   = (int*)p;

        hipMemsetAsync(ccnt, 0, 256 * sizeof(int), stream);

        const int n2 = nN * 32;
        xbf_k<<<(n2 + 255) / 256, 256, 0, stream>>>(x, xbf, n2);
        bprep_k<<<16, 256, 0, stream>>>(W, Bfrag);

        chist_k<<<256, 256, 0, stream>>>(ei, ccnt, nE, 256 * 256);
        cscan_k<<<1, 256, 0, stream>>>(ccnt, cbase, ccur, NC);
        bin_k<<<(nE + 2047) / 2048, 256, 0, stream>>>(ei, rel, ccur, binned, nE);
        fsort_k<<<NC, 1024, 0, stream>>>(binned, cbase, start, sorted, NC);

        aggemm_k<<<(nN + NPB - 1) / NPB, 512, 0, stream>>>(
            xbf, start, sorted, Bfrag, out, nN);
    } else {
        hipMemsetAsync(out, 0, (size_t)out_size * sizeof(float), stream);
        const int blocks = 2048;
        const int nWaves = blocks * (256 / 64);
        rgcn_direct_kernel<<<blocks, 256, 0, stream>>>(x, W, ei, rel, out, nE, nWaves);
    }
}

// Round 15
// 87.235 us; speedup vs baseline: 1.5459x; 1.1132x over previous
//
#include <hip/hip_runtime.h>
#include <hip/hip_bf16.h>

#define NREL 8
#define CH   64   // IN_CH == HID_CH == 64
#define NPB  16   // nodes per block in fused agg+gemm

typedef unsigned int uint32;
typedef __attribute__((ext_vector_type(8))) short bf16x8;
typedef __attribute__((ext_vector_type(4))) float f32x4;
union U4 { uint4 u; bf16x8 v; };

// ---- bf16 helpers (RNE) ----------------------------------------------------
static __device__ __forceinline__ uint32 packbf(float a, float b) {
    uint32 ua = __float_as_uint(a), ub = __float_as_uint(b);
    ua = (ua + 0x7fffu + ((ua >> 16) & 1u)) >> 16;          // low half  (elem 0 = even k)
    ub = (ub + 0x7fffu + ((ub >> 16) & 1u)) & 0xffff0000u;  // high half (elem 1 = odd k)
    return ua | ub;
}
static __device__ __forceinline__ float bflo(uint32 w) { return __uint_as_float(w << 16); }
static __device__ __forceinline__ float bfhi(uint32 w) { return __uint_as_float(w & 0xffff0000u); }

// ---------------------------------------------------------------------------
// prep2: one kernel, three independent roles by block range:
//   [0,16)            : B-fragment prep from W (r9 bprep_k)
//   [16, 16+nXB)      : xbf bf16 pack of x (r9 xbf_k)
//   [16+nXB, +256)    : coarse histogram of dst>>8, LDS-staged atomics (r13)
// ---------------------------------------------------------------------------
__global__ __launch_bounds__(256) void prep2_k(
    const float* __restrict__ x, uint32* __restrict__ xbf,
    const float* __restrict__ Wf, uint32* __restrict__ Bfrag,
    const int* __restrict__ ei, int* __restrict__ ccnt,
    int n2, int nE, int nXB)
{
    const int b = blockIdx.x;
    if (b < 16) {
        const int idx  = b * 256 + threadIdx.x;             // 0..4095
        const int lane = idx & 63;
        const int c    = (idx >> 6) & 3;
        const int ks   = idx >> 8;                          // 0..15
        const int col  = c * 16 + (lane & 15);
        const int k0   = ks * 32 + (lane >> 4) * 8;
        uint4 o;
        o.x = packbf(Wf[(k0 + 0) * 64 + col], Wf[(k0 + 1) * 64 + col]);
        o.y = packbf(Wf[(k0 + 2) * 64 + col], Wf[(k0 + 3) * 64 + col]);
        o.z = packbf(Wf[(k0 + 4) * 64 + col], Wf[(k0 + 5) * 64 + col]);
        o.w = packbf(Wf[(k0 + 6) * 64 + col], Wf[(k0 + 7) * 64 + col]);
        *(uint4*)(Bfrag + (size_t)idx * 4) = o;
    } else if (b < 16 + nXB) {
        const int i = (b - 16) * 256 + threadIdx.x;
        if (i < n2) {
            const float2 v = ((const float2*)x)[i];
            xbf[i] = packbf(v.x, v.y);
        }
    } else {
        __shared__ int h[256];
        h[threadIdx.x] = 0;
        __syncthreads();
        const int cb = b - 16 - nXB;                        // 0..255
        for (int e = cb * 256 + threadIdx.x; e < nE; e += 256 * 256)
            atomicAdd(&h[ei[nE + e] >> 8], 1);
        __syncthreads();
        const int c = threadIdx.x;
        if (h[c]) atomicAdd(&ccnt[c], h[c]);
    }
}

// ---------------------------------------------------------------------------
// Coarse exclusive scan (NC <= 256), fills cbase[0..NC] and ccur [r9].
// ---------------------------------------------------------------------------
__global__ __launch_bounds__(256) void cscan_k(
    const int* __restrict__ ccnt, int* __restrict__ cbase,
    int* __restrict__ ccur, int NC)
{
    __shared__ int sc[256];
    const int t = threadIdx.x;
    const int v = (t < NC) ? ccnt[t] : 0;
    sc[t] = v;
    __syncthreads();
    for (int off = 1; off < 256; off <<= 1) {
        int add = (t >= off) ? sc[t - off] : 0;
        __syncthreads();
        sc[t] += add;
        __syncthreads();
    }
    const int ex = sc[t] - v;
    if (t < NC) { cbase[t] = ex; ccur[t] = ex; }
    if (t == 255) cbase[NC] = sc[255];
}

// ---------------------------------------------------------------------------
// Coarse binning [r9]: per 2048-edge chunk, stage in LDS, reserve runs, write.
// Entry pack: (dlow<<24)|(rel<<16)|src.
// ---------------------------------------------------------------------------
__global__ __launch_bounds__(256) void bin_k(
    const int* __restrict__ ei, const int* __restrict__ rel,
    int* __restrict__ ccur, uint32* __restrict__ binned, int nE)
{
    __shared__ uint32        ent[2048];
    __shared__ unsigned char cid[2048];
    __shared__ int lh[256], lb[256], lc[256];

    const int t = threadIdx.x;
    lh[t] = 0;
    __syncthreads();

    const int base = blockIdx.x * 2048;
    #pragma unroll
    for (int i = 0; i < 8; ++i) {
        const int idx = t + i * 256;
        const int e   = base + idx;
        if (e < nE) {
            const int dst = ei[nE + e];
            ent[idx] = ((uint32)(dst & 255) << 24) | ((uint32)rel[e] << 16) | (uint32)ei[e];
            const int c = dst >> 8;
            cid[idx] = (unsigned char)c;
            atomicAdd(&lh[c], 1);
        } else {
            cid[idx] = 255;   // sentinel (NC <= 254 guard in launcher)
        }
    }
    __syncthreads();

    if (lh[t]) lb[t] = atomicAdd(&ccur[t], lh[t]);
    lc[t] = 0;
    __syncthreads();

    #pragma unroll
    for (int i = 0; i < 8; ++i) {
        const int idx = t + i * 256;
        const int c   = cid[idx];
        if (c != 255) {
            const int off = atomicAdd(&lc[c], 1);
            binned[lb[c] + off] = ent[idx];
        }
    }
}

// ---------------------------------------------------------------------------
// Fine sort within one coarse bucket (keyspace 2048 = dlow*8+rel), in LDS [r9].
// sorted[] keeps (rel<<16)|src for flush-on-rel-change aggregation.
// ---------------------------------------------------------------------------
__global__ __launch_bounds__(1024) void fsort_k(
    const uint32* __restrict__ binned, const int* __restrict__ cbase,
    int* __restrict__ start, int* __restrict__ sorted, int NC)
{
    __shared__ int fh[2048], fex[2048], fcur[2048], sc[1024];
    const int c  = blockIdx.x;
    const int t  = threadIdx.x;
    const int n0 = cbase[c];
    const int n1 = cbase[c + 1];

    fh[t] = 0; fh[t + 1024] = 0;
    __syncthreads();

    for (int j = n0 + t; j < n1; j += 1024) {
        const uint32 en = binned[j];
        atomicAdd(&fh[((en >> 24) << 3) | ((en >> 16) & 7)], 1);
    }
    __syncthreads();

    const int a = fh[2 * t], b = fh[2 * t + 1];
    sc[t] = a + b;
    __syncthreads();
    for (int off = 1; off < 1024; off <<= 1) {
        int add = (t >= off) ? sc[t - off] : 0;
        __syncthreads();
        sc[t] += add;
        __syncthreads();
    }
    const int ep = sc[t] - (a + b);
    fex[2 * t] = ep; fex[2 * t + 1] = ep + a;
    __syncthreads();

    fcur[t] = fex[t]; fcur[t + 1024] = fex[t + 1024];
    {
        const int k0 = c << 11;
        start[k0 + t]        = n0 + fex[t];
        start[k0 + t + 1024] = n0 + fex[t + 1024];
    }
    if (c == NC - 1 && t == 0) start[NC << 11] = n1;
    __syncthreads();

    for (int j = n0 + t; j < n1; j += 1024) {
        const uint32 en = binned[j];
        const int fk  = ((en >> 24) << 3) | ((en >> 16) & 7);
        const int off = atomicAdd(&fcur[fk], 1);
        sorted[n0 + off] = (int)(en & 0x7FFFFu);   // (rel<<16)|src
    }
}

// ---------------------------------------------------------------------------
// Fused aggregate + GEMM [r13-verified + deeper MLP]. Block = 512 threads =
// 16 half-waves, ONE node per half-wave, flat flush-on-rel-change loop now
// 8->4->1 unrolled (8 gathers in flight), flushing A-frags into an
// XOR-swizzled LDS tile; one barrier; waves 0-3 run the 16-step MFMA
// col-tiles. C/D layout per m89: col=lane&15, row=(lane>>4)*4+reg.
// ---------------------------------------------------------------------------
#define AGG_FLUSH()                                                          \
    {                                                                        \
        const int widx = (row * 256 + (prev * 2 + (l32 >> 4)) * 16 +         \
                          (l32 & 15)) ^ ((row & 7) << 2);                    \
        als[widx] = packbf(a0, a1);                                          \
    }

#define AGG_PROCESS(eu, uu)                                                  \
    {                                                                        \
        const int r_ = (int)((eu) >> 16);                                    \
        if (r_ != prev) {                                                    \
            if (prev >= 0) AGG_FLUSH();                                      \
            a0 = 0.f; a1 = 0.f;                                              \
            prev = r_;                                                       \
        }                                                                    \
        a0 += bflo(uu); a1 += bfhi(uu);                                      \
    }

__global__ __launch_bounds__(512) void aggemm_k(
    const uint32* __restrict__ xbf, const int* __restrict__ start,
    const int* __restrict__ sorted, const uint32* __restrict__ Bfrag,
    float* __restrict__ out, int nN)
{
    __shared__ uint32 als[NPB * 256];   // 16 KB

    const int t      = threadIdx.x;
    const int row    = t >> 5;          // half-wave 0..15 = node row
    const int l32    = t & 31;
    const int n_base = blockIdx.x * NPB;
    const int n      = n_base + row;

    // ---- phase 1: aggregation (one node per half-wave) ----
    #pragma unroll
    for (int z = 0; z < 8; ++z)
        als[(row * 256 + z * 32 + l32) ^ ((row & 7) << 2)] = 0u;

    if (n < nN) {
        const int kb = n * NREL;
        const int b0 = start[kb];
        const int b8 = start[kb + 8];

        int   prev = -1;
        float a0 = 0.f, a1 = 0.f;

        int j = b0;
        for (; j + 8 <= b8; j += 8) {
            const uint32 e0 = (uint32)sorted[j];
            const uint32 e1 = (uint32)sorted[j + 1];
            const uint32 e2 = (uint32)sorted[j + 2];
            const uint32 e3 = (uint32)sorted[j + 3];
            const uint32 e4 = (uint32)sorted[j + 4];
            const uint32 e5 = (uint32)sorted[j + 5];
            const uint32 e6 = (uint32)sorted[j + 6];
            const uint32 e7 = (uint32)sorted[j + 7];
            const uint32 u0 = xbf[(size_t)(e0 & 0xFFFFu) * 32 + l32];
            const uint32 u1 = xbf[(size_t)(e1 & 0xFFFFu) * 32 + l32];
            const uint32 u2 = xbf[(size_t)(e2 & 0xFFFFu) * 32 + l32];
            const uint32 u3 = xbf[(size_t)(e3 & 0xFFFFu) * 32 + l32];
            const uint32 u4 = xbf[(size_t)(e4 & 0xFFFFu) * 32 + l32];
            const uint32 u5 = xbf[(size_t)(e5 & 0xFFFFu) * 32 + l32];
            const uint32 u6 = xbf[(size_t)(e6 & 0xFFFFu) * 32 + l32];
            const uint32 u7 = xbf[(size_t)(e7 & 0xFFFFu) * 32 + l32];
            AGG_PROCESS(e0, u0);
            AGG_PROCESS(e1, u1);
            AGG_PROCESS(e2, u2);
            AGG_PROCESS(e3, u3);
            AGG_PROCESS(e4, u4);
            AGG_PROCESS(e5, u5);
            AGG_PROCESS(e6, u6);
            AGG_PROCESS(e7, u7);
        }
        for (; j + 4 <= b8; j += 4) {
            const uint32 e0 = (uint32)sorted[j];
            const uint32 e1 = (uint32)sorted[j + 1];
            const uint32 e2 = (uint32)sorted[j + 2];
            const uint32 e3 = (uint32)sorted[j + 3];
            const uint32 u0 = xbf[(size_t)(e0 & 0xFFFFu) * 32 + l32];
            const uint32 u1 = xbf[(size_t)(e1 & 0xFFFFu) * 32 + l32];
            const uint32 u2 = xbf[(size_t)(e2 & 0xFFFFu) * 32 + l32];
            const uint32 u3 = xbf[(size_t)(e3 & 0xFFFFu) * 32 + l32];
            AGG_PROCESS(e0, u0);
            AGG_PROCESS(e1, u1);
            AGG_PROCESS(e2, u2);
            AGG_PROCESS(e3, u3);
        }
        for (; j < b8; ++j) {
            const uint32 e = (uint32)sorted[j];
            const uint32 u = xbf[(size_t)(e & 0xFFFFu) * 32 + l32];
            AGG_PROCESS(e, u);
        }
        if (prev >= 0) AGG_FLUSH();
    }
    __syncthreads();

    // ---- phase 2: MFMA (waves 0-3 only) ----
    if (t < 256) {
        const int lane = t & 63;
        const int w    = t >> 6;            // col tile 0..3
        const int rl   = lane & 15;
        const int kq   = lane >> 4;

        f32x4 acc = (f32x4){0.f, 0.f, 0.f, 0.f};
        const uint32* bp = Bfrag + (size_t)lane * 4;

        #pragma unroll
        for (int ks = 0; ks < 16; ++ks) {
            const int aidx = (rl * 256 + ks * 16 + kq * 4) ^ ((rl & 7) << 2);
            U4 ua, ub;
            ua.u = *(const uint4*)(als + aidx);
            ub.u = *(const uint4*)(bp + (size_t)(ks * 4 + w) * 256);
            acc = __builtin_amdgcn_mfma_f32_16x16x32_bf16(ua.v, ub.v, acc, 0, 0, 0);
        }

        #pragma unroll
        for (int reg = 0; reg < 4; ++reg) {
            const int rr = kq * 4 + reg;
            const int nn = n_base + rr;
            if (nn < nN)
                out[(size_t)nn * 64 + w * 16 + rl] = acc[reg];
        }
    }
}

// ---------------------------------------------------------------------------
// Fallback: per-edge direct with atomics.
// ---------------------------------------------------------------------------
__global__ __launch_bounds__(256) void rgcn_direct_kernel(
    const float* __restrict__ x, const float* __restrict__ W,
    const int* __restrict__ ei, const int* __restrict__ rel,
    float* __restrict__ out, int nE, int nWaves)
{
    const int w    = (int)((blockIdx.x * 256u + threadIdx.x) >> 6);
    const int lane = threadIdx.x & 63;

    for (int e = w; e < nE; e += nWaves) {
        const int src = ei[e];
        const int dst = ei[nE + e];
        const int r   = rel[e];
        const float* xrow = x + (size_t)src * CH;
        const float* wcol = W + ((size_t)r << 12) + lane;
        float acc = 0.f;
        #pragma unroll
        for (int i = 0; i < CH; ++i) acc += xrow[i] * wcol[i * CH];
        atomicAdd(out + (size_t)dst * CH + lane, acc);
    }
}

static inline size_t align256(size_t v) { return (v + 255) & ~(size_t)255; }

extern "C" void kernel_launch(void* const* d_in, const int* in_sizes, int n_in,
                              void* d_out, int out_size, void* d_ws, size_t ws_size,
                              hipStream_t stream) {
    const float* x   = (const float*)d_in[0];
    const float* W   = (const float*)d_in[1];
    const int*   ei  = (const int*)d_in[2];
    const int*   rel = (const int*)d_in[3];
    float*       out = (float*)d_out;

    const int nN = in_sizes[0] / CH;   // 50000
    const int nE = in_sizes[3];        // 1000000
    const int NC = (nN + 255) >> 8;    // 196 coarse buckets

    // Workspace layout
    const size_t sz_xbf    = align256((size_t)nN * 32 * sizeof(uint32));        // 6.4 MB
    const size_t sz_start  = align256(((size_t)NC * 2048 + 2) * sizeof(int));   // 1.6 MB
    const size_t sz_binned = align256((size_t)nE * sizeof(uint32));             // 4 MB
    const size_t sz_sorted = align256((size_t)nE * sizeof(int));                // 4 MB
    const size_t sz_bfrag  = align256((size_t)16384 * sizeof(uint32));          // 64 KB
    const size_t sz_ccnt   = align256(256 * sizeof(int));
    const size_t sz_cbase  = align256(257 * sizeof(int));
    const size_t sz_ccur   = align256(256 * sizeof(int));
    const size_t need = sz_xbf + sz_start + sz_binned + sz_sorted +
                        sz_bfrag + sz_ccnt + sz_cbase + sz_ccur;

    if (ws_size >= need && nN <= 65024 && NC <= 254) {
        char* p = (char*)d_ws;
        uint32* xbf    = (uint32*)p;  p += sz_xbf;
        int*    start  = (int*)p;     p += sz_start;
        uint32* binned = (uint32*)p;  p += sz_binned;
        int*    sorted = (int*)p;     p += sz_sorted;
        uint32* Bfrag  = (uint32*)p;  p += sz_bfrag;
        int*    ccnt   = (int*)p;     p += sz_ccnt;
        int*    cbase  = (int*)p;     p += sz_cbase;
        int*    ccur   = (int*)p;

        hipMemsetAsync(ccnt, 0, 256 * sizeof(int), stream);

        const int n2  = nN * 32;
        const int nXB = (n2 + 255) / 256;
        prep2_k<<<16 + nXB + 256, 256, 0, stream>>>(
            x, xbf, W, Bfrag, ei, ccnt, n2, nE, nXB);

        cscan_k<<<1, 256, 0, stream>>>(ccnt, cbase, ccur, NC);
        bin_k<<<(nE + 2047) / 2048, 256, 0, stream>>>(ei, rel, ccur, binned, nE);
        fsort_k<<<NC, 1024, 0, stream>>>(binned, cbase, start, sorted, NC);

        aggemm_k<<<(nN + NPB - 1) / NPB, 512, 0, stream>>>(
            xbf, start, sorted, Bfrag, out, nN);
    } else {
        hipMemsetAsync(out, 0, (size_t)out_size * sizeof(float), stream);
        const int blocks = 2048;
        const int nWaves = blocks * (256 / 64);
        rgcn_direct_kernel<<<blocks, 256, 0, stream>>>(x, W, ei, rel, out, nE, nWaves);
    }
}

// Round 16
// 81.665 us; speedup vs baseline: 1.6513x; 1.0682x over previous
//
#include <hip/hip_runtime.h>
#include <hip/hip_bf16.h>

#define NREL 8
#define CH   64   // IN_CH == HID_CH == 64
#define NPB  16   // nodes per block in fused agg+gemm

typedef unsigned int uint32;
typedef __attribute__((ext_vector_type(8))) short bf16x8;
typedef __attribute__((ext_vector_type(4))) float f32x4;
union U4 { uint4 u; bf16x8 v; };

// ---- bf16 helpers (RNE) ----------------------------------------------------
static __device__ __forceinline__ uint32 packbf(float a, float b) {
    uint32 ua = __float_as_uint(a), ub = __float_as_uint(b);
    ua = (ua + 0x7fffu + ((ua >> 16) & 1u)) >> 16;          // low half  (elem 0 = even k)
    ub = (ub + 0x7fffu + ((ub >> 16) & 1u)) & 0xffff0000u;  // high half (elem 1 = odd k)
    return ua | ub;
}
static __device__ __forceinline__ float bflo(uint32 w) { return __uint_as_float(w << 16); }
static __device__ __forceinline__ float bfhi(uint32 w) { return __uint_as_float(w & 0xffff0000u); }

// ---------------------------------------------------------------------------
// prep2: one kernel, three independent roles by block range [r14-verified]:
//   [0,16)            : B-fragment prep from W
//   [16, 16+nXB)      : xbf bf16 pack of x
//   [16+nXB, +256)    : coarse histogram of dst>>8, LDS-staged atomics
// ---------------------------------------------------------------------------
__global__ __launch_bounds__(256) void prep2_k(
    const float* __restrict__ x, uint32* __restrict__ xbf,
    const float* __restrict__ Wf, uint32* __restrict__ Bfrag,
    const int* __restrict__ ei, int* __restrict__ ccnt,
    int n2, int nE, int nXB)
{
    const int b = blockIdx.x;
    if (b < 16) {
        const int idx  = b * 256 + threadIdx.x;             // 0..4095
        const int lane = idx & 63;
        const int c    = (idx >> 6) & 3;
        const int ks   = idx >> 8;                          // 0..15
        const int col  = c * 16 + (lane & 15);
        const int k0   = ks * 32 + (lane >> 4) * 8;
        uint4 o;
        o.x = packbf(Wf[(k0 + 0) * 64 + col], Wf[(k0 + 1) * 64 + col]);
        o.y = packbf(Wf[(k0 + 2) * 64 + col], Wf[(k0 + 3) * 64 + col]);
        o.z = packbf(Wf[(k0 + 4) * 64 + col], Wf[(k0 + 5) * 64 + col]);
        o.w = packbf(Wf[(k0 + 6) * 64 + col], Wf[(k0 + 7) * 64 + col]);
        *(uint4*)(Bfrag + (size_t)idx * 4) = o;
    } else if (b < 16 + nXB) {
        const int i = (b - 16) * 256 + threadIdx.x;
        if (i < n2) {
            const float2 v = ((const float2*)x)[i];
            xbf[i] = packbf(v.x, v.y);
        }
    } else {
        __shared__ int h[256];
        h[threadIdx.x] = 0;
        __syncthreads();
        const int cb = b - 16 - nXB;                        // 0..255
        for (int e = cb * 256 + threadIdx.x; e < nE; e += 256 * 256)
            atomicAdd(&h[ei[nE + e] >> 8], 1);
        __syncthreads();
        const int c = threadIdx.x;
        if (h[c]) atomicAdd(&ccnt[c], h[c]);
    }
}

// ---------------------------------------------------------------------------
// Coarse exclusive scan (NC <= 256), fills cbase[0..NC] and ccur [r9].
// ---------------------------------------------------------------------------
__global__ __launch_bounds__(256) void cscan_k(
    const int* __restrict__ ccnt, int* __restrict__ cbase,
    int* __restrict__ ccur, int NC)
{
    __shared__ int sc[256];
    const int t = threadIdx.x;
    const int v = (t < NC) ? ccnt[t] : 0;
    sc[t] = v;
    __syncthreads();
    for (int off = 1; off < 256; off <<= 1) {
        int add = (t >= off) ? sc[t - off] : 0;
        __syncthreads();
        sc[t] += add;
        __syncthreads();
    }
    const int ex = sc[t] - v;
    if (t < NC) { cbase[t] = ex; ccur[t] = ex; }
    if (t == 255) cbase[NC] = sc[255];
}

// ---------------------------------------------------------------------------
// Coarse binning: per 4096-edge chunk (was 2048), stage in LDS, reserve runs,
// write runs. Entry pack: (dlow<<24)|(rel<<16)|src.
// ---------------------------------------------------------------------------
__global__ __launch_bounds__(256) void bin_k(
    const int* __restrict__ ei, const int* __restrict__ rel,
    int* __restrict__ ccur, uint32* __restrict__ binned, int nE)
{
    __shared__ uint32        ent[4096];
    __shared__ unsigned char cid[4096];
    __shared__ int lh[256], lb[256], lc[256];

    const int t = threadIdx.x;
    lh[t] = 0;
    __syncthreads();

    const int base = blockIdx.x * 4096;
    #pragma unroll
    for (int i = 0; i < 16; ++i) {
        const int idx = t + i * 256;
        const int e   = base + idx;
        if (e < nE) {
            const int dst = ei[nE + e];
            ent[idx] = ((uint32)(dst & 255) << 24) | ((uint32)rel[e] << 16) | (uint32)ei[e];
            const int c = dst >> 8;
            cid[idx] = (unsigned char)c;
            atomicAdd(&lh[c], 1);
        } else {
            cid[idx] = 255;   // sentinel (NC <= 254 guard in launcher)
        }
    }
    __syncthreads();

    if (lh[t]) lb[t] = atomicAdd(&ccur[t], lh[t]);
    lc[t] = 0;
    __syncthreads();

    #pragma unroll
    for (int i = 0; i < 16; ++i) {
        const int idx = t + i * 256;
        const int c   = cid[idx];
        if (c != 255) {
            const int off = atomicAdd(&lc[c], 1);
            binned[lb[c] + off] = ent[idx];
        }
    }
}

// ---------------------------------------------------------------------------
// Fine sort within one coarse bucket (keyspace 2048 = dlow*8+rel), in LDS [r9].
// sorted[] keeps (rel<<16)|src for flush-on-rel-change aggregation.
// ---------------------------------------------------------------------------
__global__ __launch_bounds__(1024) void fsort_k(
    const uint32* __restrict__ binned, const int* __restrict__ cbase,
    int* __restrict__ start, int* __restrict__ sorted, int NC)
{
    __shared__ int fh[2048], fex[2048], fcur[2048], sc[1024];
    const int c  = blockIdx.x;
    const int t  = threadIdx.x;
    const int n0 = cbase[c];
    const int n1 = cbase[c + 1];

    fh[t] = 0; fh[t + 1024] = 0;
    __syncthreads();

    for (int j = n0 + t; j < n1; j += 1024) {
        const uint32 en = binned[j];
        atomicAdd(&fh[((en >> 24) << 3) | ((en >> 16) & 7)], 1);
    }
    __syncthreads();

    const int a = fh[2 * t], b = fh[2 * t + 1];
    sc[t] = a + b;
    __syncthreads();
    for (int off = 1; off < 1024; off <<= 1) {
        int add = (t >= off) ? sc[t - off] : 0;
        __syncthreads();
        sc[t] += add;
        __syncthreads();
    }
    const int ep = sc[t] - (a + b);
    fex[2 * t] = ep; fex[2 * t + 1] = ep + a;
    __syncthreads();

    fcur[t] = fex[t]; fcur[t + 1024] = fex[t + 1024];
    {
        const int k0 = c << 11;
        start[k0 + t]        = n0 + fex[t];
        start[k0 + t + 1024] = n0 + fex[t + 1024];
    }
    if (c == NC - 1 && t == 0) start[NC << 11] = n1;
    __syncthreads();

    for (int j = n0 + t; j < n1; j += 1024) {
        const uint32 en = binned[j];
        const int fk  = ((en >> 24) << 3) | ((en >> 16) & 7);
        const int off = atomicAdd(&fcur[fk], 1);
        sorted[n0 + off] = (int)(en & 0x7FFFFu);   // (rel<<16)|src
    }
}

// ---------------------------------------------------------------------------
// Fused aggregate + GEMM [r15 + shfl-broadcast edge codes]. Block = 512
// threads = 16 half-waves, ONE node per half-wave. Edge codes for each
// 32-chunk are loaded ONCE coalesced (lane l32 -> sorted[base+l32]) and
// broadcast via __shfl(.,j,32); only the xbf gather remains on the latency
// chain. Flush-on-rel-change into XOR-swizzled LDS A-tile; one barrier;
// waves 0-3 run the 16-step MFMA col-tiles. C/D layout per m89.
// ---------------------------------------------------------------------------
#define AGG_FLUSH()                                                          \
    {                                                                        \
        const int widx = (row * 256 + (prev * 2 + (l32 >> 4)) * 16 +         \
                          (l32 & 15)) ^ ((row & 7) << 2);                    \
        als[widx] = packbf(a0, a1);                                          \
    }

#define AGG_PROCESS(eu, uu)                                                  \
    {                                                                        \
        const int r_ = (int)((eu) >> 16);                                    \
        if (r_ != prev) {                                                    \
            if (prev >= 0) AGG_FLUSH();                                      \
            a0 = 0.f; a1 = 0.f;                                              \
            prev = r_;                                                       \
        }                                                                    \
        a0 += bflo(uu); a1 += bfhi(uu);                                      \
    }

__global__ __launch_bounds__(512) void aggemm_k(
    const uint32* __restrict__ xbf, const int* __restrict__ start,
    const int* __restrict__ sorted, const uint32* __restrict__ Bfrag,
    float* __restrict__ out, int nN)
{
    __shared__ uint32 als[NPB * 256];   // 16 KB

    const int t      = threadIdx.x;
    const int row    = t >> 5;          // half-wave 0..15 = node row
    const int l32    = t & 31;
    const int n_base = blockIdx.x * NPB;
    const int n      = n_base + row;

    // ---- phase 1: aggregation (one node per half-wave) ----
    #pragma unroll
    for (int z = 0; z < 8; ++z)
        als[(row * 256 + z * 32 + l32) ^ ((row & 7) << 2)] = 0u;

    if (n < nN) {
        const int kb = n * NREL;
        const int b0 = start[kb];
        const int b8 = start[kb + 8];

        int   prev = -1;
        float a0 = 0.f, a1 = 0.f;

        for (int base = b0; base < b8; base += 32) {
            const int cnt = min(32, b8 - base);
            const int jj  = base + l32;
            const uint32 ev = (jj < b8) ? (uint32)sorted[jj] : 0u;

            int j = 0;
            for (; j + 8 <= cnt; j += 8) {
                const uint32 e0 = __shfl(ev, j + 0, 32);
                const uint32 e1 = __shfl(ev, j + 1, 32);
                const uint32 e2 = __shfl(ev, j + 2, 32);
                const uint32 e3 = __shfl(ev, j + 3, 32);
                const uint32 e4 = __shfl(ev, j + 4, 32);
                const uint32 e5 = __shfl(ev, j + 5, 32);
                const uint32 e6 = __shfl(ev, j + 6, 32);
                const uint32 e7 = __shfl(ev, j + 7, 32);
                const uint32 u0 = xbf[(size_t)(e0 & 0xFFFFu) * 32 + l32];
                const uint32 u1 = xbf[(size_t)(e1 & 0xFFFFu) * 32 + l32];
                const uint32 u2 = xbf[(size_t)(e2 & 0xFFFFu) * 32 + l32];
                const uint32 u3 = xbf[(size_t)(e3 & 0xFFFFu) * 32 + l32];
                const uint32 u4 = xbf[(size_t)(e4 & 0xFFFFu) * 32 + l32];
                const uint32 u5 = xbf[(size_t)(e5 & 0xFFFFu) * 32 + l32];
                const uint32 u6 = xbf[(size_t)(e6 & 0xFFFFu) * 32 + l32];
                const uint32 u7 = xbf[(size_t)(e7 & 0xFFFFu) * 32 + l32];
                AGG_PROCESS(e0, u0);
                AGG_PROCESS(e1, u1);
                AGG_PROCESS(e2, u2);
                AGG_PROCESS(e3, u3);
                AGG_PROCESS(e4, u4);
                AGG_PROCESS(e5, u5);
                AGG_PROCESS(e6, u6);
                AGG_PROCESS(e7, u7);
            }
            for (; j + 4 <= cnt; j += 4) {
                const uint32 e0 = __shfl(ev, j + 0, 32);
                const uint32 e1 = __shfl(ev, j + 1, 32);
                const uint32 e2 = __shfl(ev, j + 2, 32);
                const uint32 e3 = __shfl(ev, j + 3, 32);
                const uint32 u0 = xbf[(size_t)(e0 & 0xFFFFu) * 32 + l32];
                const uint32 u1 = xbf[(size_t)(e1 & 0xFFFFu) * 32 + l32];
                const uint32 u2 = xbf[(size_t)(e2 & 0xFFFFu) * 32 + l32];
                const uint32 u3 = xbf[(size_t)(e3 & 0xFFFFu) * 32 + l32];
                AGG_PROCESS(e0, u0);
                AGG_PROCESS(e1, u1);
                AGG_PROCESS(e2, u2);
                AGG_PROCESS(e3, u3);
            }
            for (; j < cnt; ++j) {
                const uint32 e = __shfl(ev, j, 32);
                const uint32 u = xbf[(size_t)(e & 0xFFFFu) * 32 + l32];
                AGG_PROCESS(e, u);
            }
        }
        if (prev >= 0) AGG_FLUSH();
    }
    __syncthreads();

    // ---- phase 2: MFMA (waves 0-3 only) ----
    if (t < 256) {
        const int lane = t & 63;
        const int w    = t >> 6;            // col tile 0..3
        const int rl   = lane & 15;
        const int kq   = lane >> 4;

        f32x4 acc = (f32x4){0.f, 0.f, 0.f, 0.f};
        const uint32* bp = Bfrag + (size_t)lane * 4;

        #pragma unroll
        for (int ks = 0; ks < 16; ++ks) {
            const int aidx = (rl * 256 + ks * 16 + kq * 4) ^ ((rl & 7) << 2);
            U4 ua, ub;
            ua.u = *(const uint4*)(als + aidx);
            ub.u = *(const uint4*)(bp + (size_t)(ks * 4 + w) * 256);
            acc = __builtin_amdgcn_mfma_f32_16x16x32_bf16(ua.v, ub.v, acc, 0, 0, 0);
        }

        #pragma unroll
        for (int reg = 0; reg < 4; ++reg) {
            const int rr = kq * 4 + reg;
            const int nn = n_base + rr;
            if (nn < nN)
                out[(size_t)nn * 64 + w * 16 + rl] = acc[reg];
        }
    }
}

// ---------------------------------------------------------------------------
// Fallback: per-edge direct with atomics.
// ---------------------------------------------------------------------------
__global__ __launch_bounds__(256) void rgcn_direct_kernel(
    const float* __restrict__ x, const float* __restrict__ W,
    const int* __restrict__ ei, const int* __restrict__ rel,
    float* __restrict__ out, int nE, int nWaves)
{
    const int w    = (int)((blockIdx.x * 256u + threadIdx.x) >> 6);
    const int lane = threadIdx.x & 63;

    for (int e = w; e < nE; e += nWaves) {
        const int src = ei[e];
        const int dst = ei[nE + e];
        const int r   = rel[e];
        const float* xrow = x + (size_t)src * CH;
        const float* wcol = W + ((size_t)r << 12) + lane;
        float acc = 0.f;
        #pragma unroll
        for (int i = 0; i < CH; ++i) acc += xrow[i] * wcol[i * CH];
        atomicAdd(out + (size_t)dst * CH + lane, acc);
    }
}

static inline size_t align256(size_t v) { return (v + 255) & ~(size_t)255; }

extern "C" void kernel_launch(void* const* d_in, const int* in_sizes, int n_in,
                              void* d_out, int out_size, void* d_ws, size_t ws_size,
                              hipStream_t stream) {
    const float* x   = (const float*)d_in[0];
    const float* W   = (const float*)d_in[1];
    const int*   ei  = (const int*)d_in[2];
    const int*   rel = (const int*)d_in[3];
    float*       out = (float*)d_out;

    const int nN = in_sizes[0] / CH;   // 50000
    const int nE = in_sizes[3];        // 1000000
    const int NC = (nN + 255) >> 8;    // 196 coarse buckets

    // Workspace layout
    const size_t sz_xbf    = align256((size_t)nN * 32 * sizeof(uint32));        // 6.4 MB
    const size_t sz_start  = align256(((size_t)NC * 2048 + 2) * sizeof(int));   // 1.6 MB
    const size_t sz_binned = align256((size_t)nE * sizeof(uint32));             // 4 MB
    const size_t sz_sorted = align256((size_t)nE * sizeof(int));                // 4 MB
    const size_t sz_bfrag  = align256((size_t)16384 * sizeof(uint32));          // 64 KB
    const size_t sz_ccnt   = align256(256 * sizeof(int));
    const size_t sz_cbase  = align256(257 * sizeof(int));
    const size_t sz_ccur   = align256(256 * sizeof(int));
    const size_t need = sz_xbf + sz_start + sz_binned + sz_sorted +
                        sz_bfrag + sz_ccnt + sz_cbase + sz_ccur;

    if (ws_size >= need && nN <= 65024 && NC <= 254) {
        char* p = (char*)d_ws;
        uint32* xbf    = (uint32*)p;  p += sz_xbf;
        int*    start  = (int*)p;     p += sz_start;
        uint32* binned = (uint32*)p;  p += sz_binned;
        int*    sorted = (int*)p;     p += sz_sorted;
        uint32* Bfrag  = (uint32*)p;  p += sz_bfrag;
        int*    ccnt   = (int*)p;     p += sz_ccnt;
        int*    cbase  = (int*)p;     p += sz_cbase;
        int*    ccur   = (int*)p;

        hipMemsetAsync(ccnt, 0, 256 * sizeof(int), stream);

        const int n2  = nN * 32;
        const int nXB = (n2 + 255) / 256;
        prep2_k<<<16 + nXB + 256, 256, 0, stream>>>(
            x, xbf, W, Bfrag, ei, ccnt, n2, nE, nXB);

        cscan_k<<<1, 256, 0, stream>>>(ccnt, cbase, ccur, NC);
        bin_k<<<(nE + 4095) / 4096, 256, 0, stream>>>(ei, rel, ccur, binned, nE);
        fsort_k<<<NC, 1024, 0, stream>>>(binned, cbase, start, sorted, NC);

        aggemm_k<<<(nN + NPB - 1) / NPB, 512, 0, stream>>>(
            xbf, start, sorted, Bfrag, out, nN);
    } else {
        hipMemsetAsync(out, 0, (size_t)out_size * sizeof(float), stream);
        const int blocks = 2048;
        const int nWaves = blocks * (256 / 64);
        rgcn_direct_kernel<<<blocks, 256, 0, stream>>>(x, W, ei, rel, out, nE, nWaves);
    }
}

// Round 17
// 79.728 us; speedup vs baseline: 1.6914x; 1.0243x over previous
//
#include <hip/hip_runtime.h>
#include <hip/hip_bf16.h>

#define NREL 8
#define CH   64   // IN_CH == HID_CH == 64
#define NPB  16   // nodes per block in fused agg+gemm

typedef unsigned int uint32;
typedef __attribute__((ext_vector_type(8))) short bf16x8;
typedef __attribute__((ext_vector_type(4))) float f32x4;
union U4 { uint4 u; bf16x8 v; };

// ---- bf16 helpers (RNE) ----------------------------------------------------
static __device__ __forceinline__ uint32 packbf(float a, float b) {
    uint32 ua = __float_as_uint(a), ub = __float_as_uint(b);
    ua = (ua + 0x7fffu + ((ua >> 16) & 1u)) >> 16;          // low half  (elem 0 = even k)
    ub = (ub + 0x7fffu + ((ub >> 16) & 1u)) & 0xffff0000u;  // high half (elem 1 = odd k)
    return ua | ub;
}
static __device__ __forceinline__ float bflo(uint32 w) { return __uint_as_float(w << 16); }
static __device__ __forceinline__ float bfhi(uint32 w) { return __uint_as_float(w & 0xffff0000u); }

// ---------------------------------------------------------------------------
// prep2: one kernel, three independent roles by block range [r14-verified]:
//   [0,16)            : B-fragment prep from W
//   [16, 16+nXB)      : xbf bf16 pack of x
//   [16+nXB, +256)    : coarse histogram of dst>>8, LDS-staged atomics
// ---------------------------------------------------------------------------
__global__ __launch_bounds__(256) void prep2_k(
    const float* __restrict__ x, uint32* __restrict__ xbf,
    const float* __restrict__ Wf, uint32* __restrict__ Bfrag,
    const int* __restrict__ ei, int* __restrict__ ccnt,
    int n2, int nE, int nXB)
{
    const int b = blockIdx.x;
    if (b < 16) {
        const int idx  = b * 256 + threadIdx.x;             // 0..4095
        const int lane = idx & 63;
        const int c    = (idx >> 6) & 3;
        const int ks   = idx >> 8;                          // 0..15
        const int col  = c * 16 + (lane & 15);
        const int k0   = ks * 32 + (lane >> 4) * 8;
        uint4 o;
        o.x = packbf(Wf[(k0 + 0) * 64 + col], Wf[(k0 + 1) * 64 + col]);
        o.y = packbf(Wf[(k0 + 2) * 64 + col], Wf[(k0 + 3) * 64 + col]);
        o.z = packbf(Wf[(k0 + 4) * 64 + col], Wf[(k0 + 5) * 64 + col]);
        o.w = packbf(Wf[(k0 + 6) * 64 + col], Wf[(k0 + 7) * 64 + col]);
        *(uint4*)(Bfrag + (size_t)idx * 4) = o;
    } else if (b < 16 + nXB) {
        const int i = (b - 16) * 256 + threadIdx.x;
        if (i < n2) {
            const float2 v = ((const float2*)x)[i];
            xbf[i] = packbf(v.x, v.y);
        }
    } else {
        __shared__ int h[256];
        h[threadIdx.x] = 0;
        __syncthreads();
        const int cb = b - 16 - nXB;                        // 0..255
        for (int e = cb * 256 + threadIdx.x; e < nE; e += 256 * 256)
            atomicAdd(&h[ei[nE + e] >> 8], 1);
        __syncthreads();
        const int c = threadIdx.x;
        if (h[c]) atomicAdd(&ccnt[c], h[c]);
    }
}

// ---------------------------------------------------------------------------
// Coarse binning: per 4096-edge chunk, stage in LDS, reserve runs, write runs.
// cscan folded in: each block recomputes the 256-entry exclusive scan of ccnt
// via shfl wave-scan (2 barriers); reservations use zero-init cur0 cursors.
// Entry pack: (dlow<<24)|(rel<<16)|src.
// ---------------------------------------------------------------------------
__global__ __launch_bounds__(256) void bin_k(
    const int* __restrict__ ei, const int* __restrict__ rel,
    const int* __restrict__ ccnt, int* __restrict__ cur0,
    uint32* __restrict__ binned, int nE)
{
    __shared__ uint32        ent[4096];
    __shared__ unsigned char cid[4096];
    __shared__ int lh[256], lb[256], lc[256], cbl[256], wsum[4];

    const int t = threadIdx.x;

    // --- local exclusive scan of ccnt (shfl-based, 2 barriers) ---
    {
        const int v = ccnt[t];
        int s = v;
        #pragma unroll
        for (int off = 1; off < 64; off <<= 1) {
            const int u = __shfl_up(s, off, 64);
            if ((t & 63) >= off) s += u;
        }
        if ((t & 63) == 63) wsum[t >> 6] = s;
        lh[t] = 0;
        __syncthreads();
        int addv = 0;
        #pragma unroll
        for (int w = 0; w < 3; ++w)
            if (w < (t >> 6)) addv += wsum[w];
        cbl[t] = s - v + addv;      // exclusive prefix
    }
    __syncthreads();

    const int base = blockIdx.x * 4096;
    #pragma unroll
    for (int i = 0; i < 16; ++i) {
        const int idx = t + i * 256;
        const int e   = base + idx;
        if (e < nE) {
            const int dst = ei[nE + e];
            ent[idx] = ((uint32)(dst & 255) << 24) | ((uint32)rel[e] << 16) | (uint32)ei[e];
            const int c = dst >> 8;
            cid[idx] = (unsigned char)c;
            atomicAdd(&lh[c], 1);
        } else {
            cid[idx] = 255;   // sentinel (NC <= 254 guard in launcher)
        }
    }
    __syncthreads();

    if (lh[t]) lb[t] = cbl[t] + atomicAdd(&cur0[t], lh[t]);
    lc[t] = 0;
    __syncthreads();

    #pragma unroll
    for (int i = 0; i < 16; ++i) {
        const int idx = t + i * 256;
        const int c   = cid[idx];
        if (c != 255) {
            const int off = atomicAdd(&lc[c], 1);
            binned[lb[c] + off] = ent[idx];
        }
    }
}

// ---------------------------------------------------------------------------
// Fine sort within one coarse bucket (keyspace 2048 = dlow*8+rel), in LDS.
// n0/n1 computed in-block from ccnt (wave reduction); the 2048-entry scan
// uses shfl wave-scan + 16-wave-sum scan (3 barriers vs 20).
// sorted[] keeps (rel<<16)|src for flush-on-rel-change aggregation.
// ---------------------------------------------------------------------------
__global__ __launch_bounds__(1024) void fsort_k(
    const uint32* __restrict__ binned, const int* __restrict__ ccnt,
    int* __restrict__ start, int* __restrict__ sorted, int NC, int nE)
{
    __shared__ int fh[2048], fex[2048], fcur[2048], ws[16], red[16], nsh[2];
    const int c = blockIdx.x;
    const int t = threadIdx.x;

    // --- n0 = sum(ccnt[0..c)), n1 = n0 + ccnt[c]  (wave reduce, 2 barriers) ---
    {
        int v = (t < c) ? ccnt[t] : 0;
        #pragma unroll
        for (int off = 32; off > 0; off >>= 1) v += __shfl_down(v, off, 64);
        if ((t & 63) == 0) red[t >> 6] = v;
        fh[t] = 0; fh[t + 1024] = 0;
        __syncthreads();
        if (t == 0) {
            int s = 0;
            #pragma unroll
            for (int i = 0; i < 16; ++i) s += red[i];
            nsh[0] = s;
            nsh[1] = s + ccnt[c];
        }
    }
    __syncthreads();
    const int n0 = nsh[0];
    const int n1 = nsh[1];

    for (int j = n0 + t; j < n1; j += 1024) {
        const uint32 en = binned[j];
        atomicAdd(&fh[((en >> 24) << 3) | ((en >> 16) & 7)], 1);
    }
    __syncthreads();

    // --- exclusive scan over 2048 via pairwise + shfl wave-scan ---
    const int a = fh[2 * t], b = fh[2 * t + 1];
    const int p = a + b;
    int s = p;
    #pragma unroll
    for (int off = 1; off < 64; off <<= 1) {
        const int u = __shfl_up(s, off, 64);
        if ((t & 63) >= off) s += u;
    }
    if ((t & 63) == 63) ws[t >> 6] = s;
    __syncthreads();
    if (t < 16) {
        const int vv = ws[t];
        int ss = vv;
        #pragma unroll
        for (int off = 1; off < 16; off <<= 1) {
            const int u = __shfl_up(ss, off, 16);
            if (t >= off) ss += u;
        }
        ws[t] = ss - vv;            // exclusive wave offset
    }
    __syncthreads();
    const int ep = s - p + ws[t >> 6];
    fex[2 * t] = ep; fex[2 * t + 1] = ep + a;
    __syncthreads();

    fcur[t] = fex[t]; fcur[t + 1024] = fex[t + 1024];
    {
        const int k0 = c << 11;
        start[k0 + t]        = n0 + fex[t];
        start[k0 + t + 1024] = n0 + fex[t + 1024];
    }
    if (c == NC - 1 && t == 0) start[NC << 11] = n1;
    __syncthreads();

    for (int j = n0 + t; j < n1; j += 1024) {
        const uint32 en = binned[j];
        const int fk  = ((en >> 24) << 3) | ((en >> 16) & 7);
        const int off = atomicAdd(&fcur[fk], 1);
        sorted[n0 + off] = (int)(en & 0x7FFFFu);   // (rel<<16)|src
    }
}

// ---------------------------------------------------------------------------
// Fused aggregate + GEMM [r15-verified, unchanged]. Block = 512 threads =
// 16 half-waves, ONE node per half-wave. Edge codes per 32-chunk loaded once
// coalesced and broadcast via __shfl; flush-on-rel-change into XOR-swizzled
// LDS A-tile; one barrier; waves 0-3 run the 16-step MFMA col-tiles.
// C/D layout per m89: col=lane&15, row=(lane>>4)*4+reg.
// ---------------------------------------------------------------------------
#define AGG_FLUSH()                                                          \
    {                                                                        \
        const int widx = (row * 256 + (prev * 2 + (l32 >> 4)) * 16 +         \
                          (l32 & 15)) ^ ((row & 7) << 2);                    \
        als[widx] = packbf(a0, a1);                                          \
    }

#define AGG_PROCESS(eu, uu)                                                  \
    {                                                                        \
        const int r_ = (int)((eu) >> 16);                                    \
        if (r_ != prev) {                                                    \
            if (prev >= 0) AGG_FLUSH();                                      \
            a0 = 0.f; a1 = 0.f;                                              \
            prev = r_;                                                       \
        }                                                                    \
        a0 += bflo(uu); a1 += bfhi(uu);                                      \
    }

__global__ __launch_bounds__(512) void aggemm_k(
    const uint32* __restrict__ xbf, const int* __restrict__ start,
    const int* __restrict__ sorted, const uint32* __restrict__ Bfrag,
    float* __restrict__ out, int nN)
{
    __shared__ uint32 als[NPB * 256];   // 16 KB

    const int t      = threadIdx.x;
    const int row    = t >> 5;          // half-wave 0..15 = node row
    const int l32    = t & 31;
    const int n_base = blockIdx.x * NPB;
    const int n      = n_base + row;

    // ---- phase 1: aggregation (one node per half-wave) ----
    #pragma unroll
    for (int z = 0; z < 8; ++z)
        als[(row * 256 + z * 32 + l32) ^ ((row & 7) << 2)] = 0u;

    if (n < nN) {
        const int kb = n * NREL;
        const int b0 = start[kb];
        const int b8 = start[kb + 8];

        int   prev = -1;
        float a0 = 0.f, a1 = 0.f;

        for (int base = b0; base < b8; base += 32) {
            const int cnt = min(32, b8 - base);
            const int jj  = base + l32;
            const uint32 ev = (jj < b8) ? (uint32)sorted[jj] : 0u;

            int j = 0;
            for (; j + 8 <= cnt; j += 8) {
                const uint32 e0 = __shfl(ev, j + 0, 32);
                const uint32 e1 = __shfl(ev, j + 1, 32);
                const uint32 e2 = __shfl(ev, j + 2, 32);
                const uint32 e3 = __shfl(ev, j + 3, 32);
                const uint32 e4 = __shfl(ev, j + 4, 32);
                const uint32 e5 = __shfl(ev, j + 5, 32);
                const uint32 e6 = __shfl(ev, j + 6, 32);
                const uint32 e7 = __shfl(ev, j + 7, 32);
                const uint32 u0 = xbf[(size_t)(e0 & 0xFFFFu) * 32 + l32];
                const uint32 u1 = xbf[(size_t)(e1 & 0xFFFFu) * 32 + l32];
                const uint32 u2 = xbf[(size_t)(e2 & 0xFFFFu) * 32 + l32];
                const uint32 u3 = xbf[(size_t)(e3 & 0xFFFFu) * 32 + l32];
                const uint32 u4 = xbf[(size_t)(e4 & 0xFFFFu) * 32 + l32];
                const uint32 u5 = xbf[(size_t)(e5 & 0xFFFFu) * 32 + l32];
                const uint32 u6 = xbf[(size_t)(e6 & 0xFFFFu) * 32 + l32];
                const uint32 u7 = xbf[(size_t)(e7 & 0xFFFFu) * 32 + l32];
                AGG_PROCESS(e0, u0);
                AGG_PROCESS(e1, u1);
                AGG_PROCESS(e2, u2);
                AGG_PROCESS(e3, u3);
                AGG_PROCESS(e4, u4);
                AGG_PROCESS(e5, u5);
                AGG_PROCESS(e6, u6);
                AGG_PROCESS(e7, u7);
            }
            for (; j + 4 <= cnt; j += 4) {
                const uint32 e0 = __shfl(ev, j + 0, 32);
                const uint32 e1 = __shfl(ev, j + 1, 32);
                const uint32 e2 = __shfl(ev, j + 2, 32);
                const uint32 e3 = __shfl(ev, j + 3, 32);
                const uint32 u0 = xbf[(size_t)(e0 & 0xFFFFu) * 32 + l32];
                const uint32 u1 = xbf[(size_t)(e1 & 0xFFFFu) * 32 + l32];
                const uint32 u2 = xbf[(size_t)(e2 & 0xFFFFu) * 32 + l32];
                const uint32 u3 = xbf[(size_t)(e3 & 0xFFFFu) * 32 + l32];
                AGG_PROCESS(e0, u0);
                AGG_PROCESS(e1, u1);
                AGG_PROCESS(e2, u2);
                AGG_PROCESS(e3, u3);
            }
            for (; j < cnt; ++j) {
                const uint32 e = __shfl(ev, j, 32);
                const uint32 u = xbf[(size_t)(e & 0xFFFFu) * 32 + l32];
                AGG_PROCESS(e, u);
            }
        }
        if (prev >= 0) AGG_FLUSH();
    }
    __syncthreads();

    // ---- phase 2: MFMA (waves 0-3 only) ----
    if (t < 256) {
        const int lane = t & 63;
        const int w    = t >> 6;            // col tile 0..3
        const int rl   = lane & 15;
        const int kq   = lane >> 4;

        f32x4 acc = (f32x4){0.f, 0.f, 0.f, 0.f};
        const uint32* bp = Bfrag + (size_t)lane * 4;

        #pragma unroll
        for (int ks = 0; ks < 16; ++ks) {
            const int aidx = (rl * 256 + ks * 16 + kq * 4) ^ ((rl & 7) << 2);
            U4 ua, ub;
            ua.u = *(const uint4*)(als + aidx);
            ub.u = *(const uint4*)(bp + (size_t)(ks * 4 + w) * 256);
            acc = __builtin_amdgcn_mfma_f32_16x16x32_bf16(ua.v, ub.v, acc, 0, 0, 0);
        }

        #pragma unroll
        for (int reg = 0; reg < 4; ++reg) {
            const int rr = kq * 4 + reg;
            const int nn = n_base + rr;
            if (nn < nN)
                out[(size_t)nn * 64 + w * 16 + rl] = acc[reg];
        }
    }
}

// ---------------------------------------------------------------------------
// Fallback: per-edge direct with atomics.
// ---------------------------------------------------------------------------
__global__ __launch_bounds__(256) void rgcn_direct_kernel(
    const float* __restrict__ x, const float* __restrict__ W,
    const int* __restrict__ ei, const int* __restrict__ rel,
    float* __restrict__ out, int nE, int nWaves)
{
    const int w    = (int)((blockIdx.x * 256u + threadIdx.x) >> 6);
    const int lane = threadIdx.x & 63;

    for (int e = w; e < nE; e += nWaves) {
        const int src = ei[e];
        const int dst = ei[nE + e];
        const int r   = rel[e];
        const float* xrow = x + (size_t)src * CH;
        const float* wcol = W + ((size_t)r << 12) + lane;
        float acc = 0.f;
        #pragma unroll
        for (int i = 0; i < CH; ++i) acc += xrow[i] * wcol[i * CH];
        atomicAdd(out + (size_t)dst * CH + lane, acc);
    }
}

static inline size_t align256(size_t v) { return (v + 255) & ~(size_t)255; }

extern "C" void kernel_launch(void* const* d_in, const int* in_sizes, int n_in,
                              void* d_out, int out_size, void* d_ws, size_t ws_size,
                              hipStream_t stream) {
    const float* x   = (const float*)d_in[0];
    const float* W   = (const float*)d_in[1];
    const int*   ei  = (const int*)d_in[2];
    const int*   rel = (const int*)d_in[3];
    float*       out = (float*)d_out;

    const int nN = in_sizes[0] / CH;   // 50000
    const int nE = in_sizes[3];        // 1000000
    const int NC = (nN + 255) >> 8;    // 196 coarse buckets

    // Workspace layout
    const size_t sz_xbf    = align256((size_t)nN * 32 * sizeof(uint32));        // 6.4 MB
    const size_t sz_start  = align256(((size_t)NC * 2048 + 2) * sizeof(int));   // 1.6 MB
    const size_t sz_binned = align256((size_t)nE * sizeof(uint32));             // 4 MB
    const size_t sz_sorted = align256((size_t)nE * sizeof(int));                // 4 MB
    const size_t sz_bfrag  = align256((size_t)16384 * sizeof(uint32));          // 64 KB
    const size_t sz_ccnt   = align256(256 * sizeof(int));
    const size_t sz_cur0   = align256(256 * sizeof(int));
    const size_t need = sz_xbf + sz_start + sz_binned + sz_sorted +
                        sz_bfrag + sz_ccnt + sz_cur0;

    if (ws_size >= need && nN <= 65024 && NC <= 254) {
        char* p = (char*)d_ws;
        uint32* xbf    = (uint32*)p;  p += sz_xbf;
        int*    start  = (int*)p;     p += sz_start;
        uint32* binned = (uint32*)p;  p += sz_binned;
        int*    sorted = (int*)p;     p += sz_sorted;
        uint32* Bfrag  = (uint32*)p;  p += sz_bfrag;
        int*    ccnt   = (int*)p;     p += sz_ccnt;
        int*    cur0   = (int*)p;

        // one memset covers ccnt + cur0 (contiguous)
        hipMemsetAsync(ccnt, 0, sz_ccnt + sz_cur0, stream);

        const int n2  = nN * 32;
        const int nXB = (n2 + 255) / 256;
        prep2_k<<<16 + nXB + 256, 256, 0, stream>>>(
            x, xbf, W, Bfrag, ei, ccnt, n2, nE, nXB);

        bin_k<<<(nE + 4095) / 4096, 256, 0, stream>>>(ei, rel, ccnt, cur0, binned, nE);
        fsort_k<<<NC, 1024, 0, stream>>>(binned, ccnt, start, sorted, NC, nE);

        aggemm_k<<<(nN + NPB - 1) / NPB, 512, 0, stream>>>(
            xbf, start, sorted, Bfrag, out, nN);
    } else {
        hipMemsetAsync(out, 0, (size_t)out_size * sizeof(float), stream);
        const int blocks = 2048;
        const int nWaves = blocks * (256 / 64);
        rgcn_direct_kernel<<<blocks, 256, 0, stream>>>(x, W, ei, rel, out, nE, nWaves);
    }
}